// Round 11
// baseline (700.559 us; speedup 1.0000x reference)
//
#include <hip/hip_runtime.h>
#include <hip/hip_bf16.h>
#include <hip/hip_fp8.h>

typedef unsigned short bfu;
typedef unsigned char f8u;
typedef __attribute__((ext_vector_type(8))) short short8;
typedef __attribute__((ext_vector_type(4))) float f32x4;

__device__ __forceinline__ bfu f2bf(float f) {
  return __builtin_bit_cast(bfu, __float2bfloat16(f));
}
__device__ __forceinline__ f8u f2f8(float f) {
  __hip_fp8_e4m3 t(f);
  return t.__x;
}

__device__ __forceinline__ void gld16(const void* g, void* l) {
  __builtin_amdgcn_global_load_lds(
      (const __attribute__((address_space(1))) void*)g,
      (__attribute__((address_space(3))) void*)l, 16, 0, 0);
}

// ---- swizzle for [rows][64]-bf16 tiles (128B rows, 8 x 16B slots per row)
__device__ __forceinline__ int swz8(int row, int sl) {
  return (row << 7) + (((sl ^ (row & 7)) & 7) << 4);
}

// ---- swizzle for [rows][32]-bf16 tiles (64B rows) used by row_gemm --------
__device__ __forceinline__ int swz(int row, int slot) {
  const int unit = row >> 1;
  const int s8 = ((row & 1) << 2) | slot;
  return (unit << 7) + (((s8 ^ unit) & 7) << 4) + ((s8 >> 3) << 7);
}
__device__ __forceinline__ void unswz(int p, int& row, int& colel) {
  const int unit = p >> 7;
  const int s8 = ((p >> 4) & 7) ^ (unit & 7);
  row = (unit << 1) | (s8 >> 2);
  colel = (s8 & 3) << 3;
}

// ---------------- weight prep in ONE launch ---------------------------------
// wqkvT/woT: bf16 [n][k]; w1T/w2T: fp8-e4m3 [n][k] for the FFN pair.
__global__ void transpose_all(const float* __restrict__ Wq, const float* __restrict__ Wk,
                              const float* __restrict__ Wv, const float* __restrict__ Wo,
                              const float* __restrict__ W1, const float* __restrict__ W2,
                              bfu* __restrict__ wqkvT, bfu* __restrict__ woT,
                              f8u* __restrict__ w1T, f8u* __restrict__ w2T) {
  int idx = blockIdx.x * 256 + threadIdx.x;
  if (idx < 4 * 147456) {
    int r = idx / 147456, i = idx - r * 147456;
    int k = i / 384, n = i - k * 384;
    const float* W = r == 0 ? Wq : r == 1 ? Wk : r == 2 ? Wv : Wo;
    bfu* dst = r < 3 ? wqkvT + r * 147456 : woT;
    dst[n * 384 + k] = f2bf(W[i]);
  } else if (idx < 4 * 147456 + 589824) {
    int i = idx - 4 * 147456;                    // W1: [384][1536]
    int k = i / 1536, n = i - k * 1536;
    w1T[n * 384 + k] = f2f8(W1[i]);
  } else if (idx < 4 * 147456 + 2 * 589824) {
    int i = idx - 4 * 147456 - 589824;           // W2: [1536][384]
    int k = i / 384, n = i - k * 384;
    w2T[(size_t)n * 1536 + k] = f2f8(W2[i]);
  }
}

// ---------------- LayerNorm: one wave per row of 384 ------------------------
__launch_bounds__(256)
__global__ void ln_kernel(const float* __restrict__ in, const float* __restrict__ g,
                          const float* __restrict__ be, bfu* __restrict__ out) {
  const int wv = threadIdx.x >> 6, ln = threadIdx.x & 63;
  const size_t row = (size_t)blockIdx.x * 4 + wv;
  const float* p = in + row * 384;
  float v[6], s = 0.f, ss = 0.f;
#pragma unroll
  for (int i = 0; i < 6; i++) { v[i] = p[i * 64 + ln]; s += v[i]; ss += v[i] * v[i]; }
#pragma unroll
  for (int m = 1; m < 64; m <<= 1) { s += __shfl_xor(s, m); ss += __shfl_xor(ss, m); }
  const float mean = s * (1.f / 384.f);
  const float rs = rsqrtf(ss * (1.f / 384.f) - mean * mean + 1e-5f);
  bfu* q = out + row * 384;
#pragma unroll
  for (int i = 0; i < 6; i++) {
    const int c = i * 64 + ln;
    q[c] = f2bf((v[i] - mean) * rs * g[c] + be[c]);
  }
}

// ---------------- counted-vmcnt GEMM, bf16 (QKV) ----------------------------
// BM=256, BN=128, BK=64, 512 thr = 8 waves (2m x 4n), wave tile 128x32.
// 3 LDS bufs; stage spread [2,2,1,1]; vmcnt(6) at group tails only. (R9 cfg.)
template <int BIAS, int RELU, int RES, int OUTBF>
__launch_bounds__(512)
__global__ void gemm3b(const bfu* __restrict__ A, const bfu* __restrict__ Bt,
                       const float* __restrict__ bias, const float* __restrict__ res,
                       void* __restrict__ Cout, int N, int K, int ntn) {
  __shared__ char sm[3 * 49152];
  const int tid = threadIdx.x;
  const int wv = tid >> 6, ln = tid & 63;
  const int cpx = gridDim.x >> 3;
  const int wg = (blockIdx.x & 7) * cpx + (blockIdx.x >> 3);
  const int bm = wg / ntn, bn = wg - bm * ntn;
  const int m0 = bm << 8, n0 = bn << 7;
  const int wr = wv >> 2, wc = wv & 3;
  const int fr = ln & 15, fslot = ln >> 4;
  const int lr = ln >> 3, lsl = (ln & 7) ^ lr;

  f32x4 acc[8][2];
#pragma unroll
  for (int i = 0; i < 8; i++)
#pragma unroll
    for (int j = 0; j < 2; j++) acc[i][j] = f32x4{0.f, 0.f, 0.f, 0.f};

  auto stageA = [&](int dbuf, int kt, int half) {
    char* smA = sm + dbuf * 49152;
    const int col = (kt << 6) + (lsl << 3);
#pragma unroll
    for (int i = 0; i < 2; ++i) {
      const int c = (wv << 2) + (half << 1) + i;
      gld16(A + (size_t)(m0 + (c << 3) + lr) * K + col, smA + (c << 10));
    }
  };
  auto stageB = [&](int dbuf, int kt, int j) {
    char* smB = sm + dbuf * 49152 + 32768;
    const int col = (kt << 6) + (lsl << 3);
    const int c = (wv << 1) + j;
    gld16(Bt + (size_t)(n0 + (c << 3) + lr) * K + col, smB + (c << 10));
  };

  const int nk = K >> 6;
  stageA(0, 0, 0); stageA(0, 0, 1); stageB(0, 0, 0); stageB(0, 0, 1);
  stageA(1, 1, 0); stageA(1, 1, 1); stageB(1, 1, 0); stageB(1, 1, 1);
  asm volatile("s_waitcnt vmcnt(6)" ::: "memory");
  __builtin_amdgcn_s_barrier();

  int cb = 0;
  for (int k = 0; k < nk; ++k) {
    const char* smA = sm + cb * 49152;
    const char* smB = smA + 32768;
    int sb = cb + 2; if (sb >= 3) sb -= 3;
    const bool st = (k + 2) < nk;
#pragma unroll
    for (int mh = 0; mh < 2; ++mh) {
      short8 af[4][2];
#pragma unroll
      for (int i = 0; i < 4; ++i)
#pragma unroll
        for (int ks = 0; ks < 2; ++ks)
          af[i][ks] = *(const short8*)(smA +
              swz8(wr * 128 + mh * 64 + i * 16 + fr, ks * 4 + fslot));
#pragma unroll
      for (int nh = 0; nh < 2; ++nh) {
        short8 bf[2];
#pragma unroll
        for (int ks = 0; ks < 2; ++ks)
          bf[ks] = *(const short8*)(smB + swz8(wc * 32 + nh * 16 + fr, ks * 4 + fslot));
        if (st) {
          if (mh == 0 && nh == 0) stageA(sb, k + 2, 0);
          if (mh == 0 && nh == 1) stageA(sb, k + 2, 1);
          if (mh == 1 && nh == 0) stageB(sb, k + 2, 0);
          if (mh == 1 && nh == 1) stageB(sb, k + 2, 1);
        }
        __builtin_amdgcn_s_barrier();
        asm volatile("s_waitcnt lgkmcnt(0)" ::: "memory");
        __builtin_amdgcn_sched_barrier(0);
        __builtin_amdgcn_s_setprio(1);
#pragma unroll
        for (int i = 0; i < 4; ++i)
#pragma unroll
          for (int ks = 0; ks < 2; ++ks)
            acc[mh * 4 + i][nh] = __builtin_amdgcn_mfma_f32_16x16x32_bf16(
                af[i][ks], bf[ks], acc[mh * 4 + i][nh], 0, 0, 0);
        __builtin_amdgcn_s_setprio(0);
        if (mh == 1 && nh == 1 && k + 1 < nk) {
          if (st) asm volatile("s_waitcnt vmcnt(6)" ::: "memory");
          else    asm volatile("s_waitcnt vmcnt(0)" ::: "memory");
        }
        __builtin_amdgcn_s_barrier();
      }
    }
    cb = (cb + 1 == 3) ? 0 : cb + 1;
  }

  const int rq = (ln >> 4) << 2;
#pragma unroll
  for (int mi = 0; mi < 8; mi++) {
#pragma unroll
    for (int ni = 0; ni < 2; ni++) {
      const int row = m0 + wr * 128 + mi * 16 + rq;
      const int col = n0 + wc * 32 + ni * 16 + fr;
      float bv = 0.f;
      if (BIAS) bv = bias[col];
#pragma unroll
      for (int r = 0; r < 4; r++) {
        float v = acc[mi][ni][r] + bv;
        if (RELU) v = fmaxf(v, 0.f);
        const size_t idx = (size_t)(row + r) * N + col;
        if (RES) v += res[idx];
        if (OUTBF) ((bfu*)Cout)[idx] = f2bf(v);
        else       ((float*)Cout)[idx] = v;
      }
    }
  }
}

// ---------------- counted-vmcnt GEMM, fp8-e4m3 (FFN1/FFN2) ------------------
// Same skeleton, A and Bt in fp8 (1B elems). Per buf: A[256][64]=16KB +
// B[128][64]=8KB = 24KB; 3 bufs = 72KB -> 2 blocks/CU. 3 loads/K-tile/wave,
// vmcnt(3) at group tails. Linear LDS (conflicts proven free in this regime).
// Frags: 8 fp8/lane, identical lane->k formula for A and B (permutation-safe).
// OUT: 0 = fp32 (+RES), 1 = fp8.
template <int BIAS, int RELU, int RES, int OUTF8>
__launch_bounds__(512)
__global__ void gemm3f8(const f8u* __restrict__ A, const f8u* __restrict__ Bt,
                        const float* __restrict__ bias, const float* __restrict__ res,
                        void* __restrict__ Cout, int N, int K, int ntn) {
  __shared__ char sm[3 * 24576];    // per buf: A 16KB + B 8KB
  const int tid = threadIdx.x;
  const int wv = tid >> 6, ln = tid & 63;
  const int cpx = gridDim.x >> 3;   // grid % 8 == 0 at all call sites
  const int wg = (blockIdx.x & 7) * cpx + (blockIdx.x >> 3);
  const int bm = wg / ntn, bn = wg - bm * ntn;
  const int m0 = bm << 8, n0 = bn << 7;
  const int wr = wv >> 2, wc = wv & 3;   // wave tile 128x32
  const int fr = ln & 15, fslot = ln >> 4;

  f32x4 acc[8][2];
#pragma unroll
  for (int i = 0; i < 8; i++)
#pragma unroll
    for (int j = 0; j < 2; j++) acc[i][j] = f32x4{0.f, 0.f, 0.f, 0.f};

  // staging: chunk = 16 rows x 64B = 1KB; lane -> row c*16+(ln>>2), byte (ln&3)*16
  auto stageA = [&](int dbuf, int kt, int half) {  // 1 load
    char* smA = sm + dbuf * 24576;
    const int c = (wv << 1) + half;                // A chunks 0..15
    gld16(A + (size_t)(m0 + (c << 4) + (ln >> 2)) * K + (kt << 6) + ((ln & 3) << 4),
          smA + (c << 10));
  };
  auto stageB = [&](int dbuf, int kt) {            // 1 load
    char* smB = sm + dbuf * 24576 + 16384;
    const int c = wv;                              // B chunks 0..7
    gld16(Bt + (size_t)(n0 + (c << 4) + (ln >> 2)) * K + (kt << 6) + ((ln & 3) << 4),
          smB + (c << 10));
  };

  const int nk = K >> 6;
  stageA(0, 0, 0); stageA(0, 0, 1); stageB(0, 0);
  stageA(1, 1, 0); stageA(1, 1, 1); stageB(1, 1);
  asm volatile("s_waitcnt vmcnt(3)" ::: "memory");  // K-tile 0 ready; 1 in flight
  __builtin_amdgcn_s_barrier();

  int cb = 0;
  for (int k = 0; k < nk; ++k) {
    const char* smA = sm + cb * 24576;
    const char* smB = smA + 16384;
    int sb = cb + 2; if (sb >= 3) sb -= 3;
    const bool st = (k + 2) < nk;
#pragma unroll
    for (int mh = 0; mh < 2; ++mh) {
      long af[4][2];
#pragma unroll
      for (int i = 0; i < 4; ++i)
#pragma unroll
        for (int ks = 0; ks < 2; ++ks)
          af[i][ks] = *(const long*)(smA +
              (wr * 128 + mh * 64 + i * 16 + fr) * 64 + ks * 32 + fslot * 8);
#pragma unroll
      for (int nh = 0; nh < 2; ++nh) {
        long bf[2];
#pragma unroll
        for (int ks = 0; ks < 2; ++ks)
          bf[ks] = *(const long*)(smB +
              (wc * 32 + nh * 16 + fr) * 64 + ks * 32 + fslot * 8);
        if (st) {
          if (mh == 0 && nh == 0) stageA(sb, k + 2, 0);
          if (mh == 0 && nh == 1) stageA(sb, k + 2, 1);
          if (mh == 1 && nh == 0) stageB(sb, k + 2);
        }
        __builtin_amdgcn_s_barrier();
        asm volatile("s_waitcnt lgkmcnt(0)" ::: "memory");
        __builtin_amdgcn_sched_barrier(0);
        __builtin_amdgcn_s_setprio(1);
#pragma unroll
        for (int i = 0; i < 4; ++i)
#pragma unroll
          for (int ks = 0; ks < 2; ++ks)
            acc[mh * 4 + i][nh] = __builtin_amdgcn_mfma_f32_16x16x32_fp8_fp8(
                af[i][ks], bf[ks], acc[mh * 4 + i][nh], 0, 0, 0);
        __builtin_amdgcn_s_setprio(0);
        if (mh == 1 && nh == 1 && k + 1 < nk) {
          if (st) asm volatile("s_waitcnt vmcnt(3)" ::: "memory");
          else    asm volatile("s_waitcnt vmcnt(0)" ::: "memory");
        }
        __builtin_amdgcn_s_barrier();
      }
    }
    cb = (cb + 1 == 3) ? 0 : cb + 1;
  }

  const int rq = (ln >> 4) << 2;
#pragma unroll
  for (int mi = 0; mi < 8; mi++) {
#pragma unroll
    for (int ni = 0; ni < 2; ni++) {
      const int row = m0 + wr * 128 + mi * 16 + rq;
      const int col = n0 + wc * 32 + ni * 16 + fr;
      float bv = 0.f;
      if (BIAS) bv = bias[col];
#pragma unroll
      for (int r = 0; r < 4; r++) {
        float v = acc[mi][ni][r] + bv;
        if (RELU) v = fmaxf(v, 0.f);
        const size_t idx = (size_t)(row + r) * N + col;
        if (RES) v += res[idx];
        if (OUTF8) ((f8u*)Cout)[idx] = f2f8(v);
        else       ((float*)Cout)[idx] = v;
      }
    }
  }
}

// ---------------- full-row GEMM (proj + LN2 fusion): C[M,384] ---------------
// Output h2 as fp8-e4m3 (feeds fp8 FFN1).
__launch_bounds__(512)
__global__ void row_gemm(const bfu* __restrict__ A, const bfu* __restrict__ Bt,
                         const float* __restrict__ bias, const float* __restrict__ res,
                         const float* __restrict__ g, const float* __restrict__ be,
                         f8u* __restrict__ Cout, int K) {
  __shared__ bfu a_sm[4][128 * 32];
  __shared__ bfu b_sm[4][384 * 32];
  __shared__ float lnp[4][128][2];
  const int tid = threadIdx.x;
  const int wv = tid >> 6, ln = tid & 63;
  const int wr = wv >> 2, wc = wv & 3;
  const int fr = ln & 15, fslot = ln >> 4;
  const int m0 = blockIdx.x << 7;

  f32x4 acc[4][6];
#pragma unroll
  for (int i = 0; i < 4; i++)
#pragma unroll
    for (int j = 0; j < 6; j++) acc[i][j] = f32x4{0.f, 0.f, 0.f, 0.f};

  auto stage = [&](int buf, int kt) {
#pragma unroll
    for (int i = 0; i < 4; ++i) {
      const int c = wv * 4 + i;
      const int cc = (c < 8) ? c : (c - 8);
      const int p = cc * 1024 + (ln << 4);
      int r, colel;
      unswz(p, r, colel);
      const int col = kt * 32 + colel;
      if (c < 8)
        gld16(A + (size_t)(m0 + r) * K + col, (char*)a_sm[buf] + cc * 1024);
      else
        gld16(Bt + (size_t)r * K + col, (char*)b_sm[buf] + cc * 1024);
    }
  };

  const int nk = K >> 5;
#pragma unroll
  for (int i = 0; i < 3; ++i)
    if (i < nk) stage(i, i);

  for (int kt = 0; kt < nk; ++kt) {
    const int rem = nk - 1 - kt;
    if (rem >= 2)      asm volatile("s_waitcnt vmcnt(8)" ::: "memory");
    else if (rem == 1) asm volatile("s_waitcnt vmcnt(4)" ::: "memory");
    else               asm volatile("s_waitcnt vmcnt(0)" ::: "memory");
    __builtin_amdgcn_s_barrier();
    __builtin_amdgcn_sched_barrier(0);
    if (kt + 3 < nk) stage((kt + 3) & 3, kt + 3);
    const int cb = kt & 3;
    short8 af[4], bfr[6];
#pragma unroll
    for (int mi = 0; mi < 4; mi++)
      af[mi] = *(const short8*)((const char*)a_sm[cb] + swz(wr * 64 + mi * 16 + fr, fslot));
#pragma unroll
    for (int ni = 0; ni < 6; ni++)
      bfr[ni] = *(const short8*)((const char*)b_sm[cb] + swz(wc * 96 + ni * 16 + fr, fslot));
    __builtin_amdgcn_s_setprio(1);
#pragma unroll
    for (int mi = 0; mi < 4; mi++)
#pragma unroll
      for (int ni = 0; ni < 6; ni++)
        acc[mi][ni] = __builtin_amdgcn_mfma_f32_16x16x32_bf16(af[mi], bfr[ni], acc[mi][ni], 0, 0, 0);
    __builtin_amdgcn_s_setprio(0);
  }

  const int rq = (ln >> 4) << 2;
#pragma unroll
  for (int mi = 0; mi < 4; mi++) {
    const int row = wr * 64 + mi * 16 + rq;
#pragma unroll
    for (int ni = 0; ni < 6; ni++) {
      const int col = wc * 96 + ni * 16 + fr;
      const float bv = bias[col];
#pragma unroll
      for (int r = 0; r < 4; r++)
        acc[mi][ni][r] += bv + res[(size_t)(m0 + row + r) * 384 + col];
    }
  }

#pragma unroll
  for (int mi = 0; mi < 4; mi++) {
    float s[4] = {0.f, 0.f, 0.f, 0.f}, ss[4] = {0.f, 0.f, 0.f, 0.f};
#pragma unroll
    for (int ni = 0; ni < 6; ni++)
#pragma unroll
      for (int r = 0; r < 4; r++) {
        const float v = acc[mi][ni][r];
        s[r] += v; ss[r] += v * v;
      }
#pragma unroll
    for (int m = 1; m < 16; m <<= 1)
#pragma unroll
      for (int r = 0; r < 4; r++) {
        s[r] += __shfl_xor(s[r], m);
        ss[r] += __shfl_xor(ss[r], m);
      }
    if (fr == 0) {
#pragma unroll
      for (int r = 0; r < 4; r++) {
        lnp[wc][wr * 64 + mi * 16 + rq + r][0] = s[r];
        lnp[wc][wr * 64 + mi * 16 + rq + r][1] = ss[r];
      }
    }
  }
  __syncthreads();
#pragma unroll
  for (int mi = 0; mi < 4; mi++) {
#pragma unroll
    for (int r = 0; r < 4; r++) {
      const int row = wr * 64 + mi * 16 + rq + r;
      const float sm = lnp[0][row][0] + lnp[1][row][0] + lnp[2][row][0] + lnp[3][row][0];
      const float sq = lnp[0][row][1] + lnp[1][row][1] + lnp[2][row][1] + lnp[3][row][1];
      const float mean = sm * (1.f / 384.f);
      const float rs = rsqrtf(sq * (1.f / 384.f) - mean * mean + 1e-5f);
#pragma unroll
      for (int ni = 0; ni < 6; ni++) {
        const int col = wc * 96 + ni * 16 + fr;
        Cout[(size_t)(m0 + row) * 384 + col] =
            f2f8((acc[mi][ni][r] - mean) * rs * g[col] + be[col]);
      }
    }
  }
}

// ---------------- fused causal attention: 1 block per (b,h), 8 waves --------
#define KPAD 72
#define VPAD 264
#define PPAD 264

__launch_bounds__(512)
__global__ void attn_kernel(const bfu* __restrict__ qkv, bfu* __restrict__ ob) {
  __shared__ bfu k_sm[256 * KPAD];
  __shared__ bfu vt_sm[64 * VPAD];
  __shared__ bfu p_sm[8 * 16 * PPAD];
  const int b = blockIdx.x / 6, h = blockIdx.x - b * 6;
  const int tid = threadIdx.x;
  const int wv = tid >> 6, ln = tid & 63;
  const int fr = ln & 15, fc = (ln >> 4) << 3;
  const size_t inbase = (size_t)b * 256 * 1152 + h * 64;
  const bfu* qb = qkv + inbase;
  const bfu* kb = qkv + inbase + 384;
  const bfu* vb = qkv + inbase + 768;
  const size_t obase = (size_t)b * 256 * 384 + h * 64;

  {
    const int row = tid >> 1;
    const int dh = (tid & 1) << 5;
    const bfu* kg = kb + (size_t)row * 1152 + dh;
    const bfu* vg = vb + (size_t)row * 1152 + dh;
#pragma unroll
    for (int i = 0; i < 4; i++) {
      short8 t8 = *(const short8*)(kg + i * 8);
      *(short8*)&k_sm[row * KPAD + dh + i * 8] = t8;
      short8 v8 = *(const short8*)(vg + i * 8);
#pragma unroll
      for (int j = 0; j < 8; j++)
        vt_sm[(dh + i * 8 + j) * VPAD + row] = (bfu)v8[j];
    }
  }
  __syncthreads();

  bfu* pw = &p_sm[wv * 16 * PPAD];
  const int rq = (ln >> 4) << 2;

#pragma unroll
  for (int si = 0; si < 2; ++si) {
    const int s = si ? (15 - wv) : wv;
    const int qr0 = s << 4;
    const int nf = s + 1;
    short8 aq[2];
#pragma unroll
    for (int dc = 0; dc < 2; dc++)
      aq[dc] = *(const short8*)(qb + (size_t)(qr0 + fr) * 1152 + dc * 32 + fc);

    f32x4 sacc[16];
#pragma unroll
    for (int f = 0; f < 16; f++) sacc[f] = f32x4{0.f, 0.f, 0.f, 0.f};
#pragma unroll
    for (int f = 0; f < 16; f++) if (f < nf) {
#pragma unroll
      for (int dc = 0; dc < 2; dc++) {
        short8 kf = *(const short8*)&k_sm[(f * 16 + fr) * KPAD + dc * 32 + fc];
        sacc[f] = __builtin_amdgcn_mfma_f32_16x16x32_bf16(aq[dc], kf, sacc[f], 0, 0, 0);
      }
    }
    float mr[4] = {-3e38f, -3e38f, -3e38f, -3e38f};
#pragma unroll
    for (int f = 0; f < 16; f++) if (f < nf) {
#pragma unroll
      for (int r = 0; r < 4; r++) {
        float sv = sacc[f][r] * 0.125f;
        if (f * 16 + fr > qr0 + rq + r) sv = -3e38f;
        sacc[f][r] = sv;
        mr[r] = fmaxf(mr[r], sv);
      }
    }
#pragma unroll
    for (int msk = 1; msk < 16; msk <<= 1) {
#pragma unroll
      for (int r = 0; r < 4; r++) mr[r] = fmaxf(mr[r], __shfl_xor(mr[r], msk));
    }
    float ls[4] = {0.f, 0.f, 0.f, 0.f};
#pragma unroll
    for (int f = 0; f < 16; f++) if (f < nf) {
#pragma unroll
      for (int r = 0; r < 4; r++) {
        float p = __expf(sacc[f][r] - mr[r]);
        sacc[f][r] = p;
        ls[r] += p;
      }
    }
#pragma unroll
    for (int msk = 1; msk < 16; msk <<= 1) {
#pragma unroll
      for (int r = 0; r < 4; r++) ls[r] += __shfl_xor(ls[r], msk);
    }
#pragma unroll
    for (int f = 0; f < 16; f++) if (f < nf) {
#pragma unroll
      for (int r = 0; r < 4; r++)
        pw[(rq + r) * PPAD + f * 16 + fr] = f2bf(sacc[f][r]);
    }
    if (nf & 1) {
#pragma unroll
      for (int r = 0; r < 4; r++) pw[(rq + r) * PPAD + nf * 16 + fr] = 0;
    }
    f32x4 oc[4];
#pragma unroll
    for (int n = 0; n < 4; n++) oc[n] = f32x4{0.f, 0.f, 0.f, 0.f};
    const int kcs = (nf + 1) >> 1;
#pragma unroll
    for (int kc = 0; kc < 8; ++kc) if (kc < kcs) {
      short8 pa = *(const short8*)&pw[fr * PPAD + kc * 32 + fc];
#pragma unroll
      for (int n = 0; n < 4; n++) {
        short8 vf = *(const short8*)&vt_sm[(n * 16 + fr) * VPAD + kc * 32 + fc];
        oc[n] = __builtin_amdgcn_mfma_f32_16x16x32_bf16(pa, vf, oc[n], 0, 0, 0);
      }
    }
    float inv[4];
#pragma unroll
    for (int r = 0; r < 4; r++) inv[r] = 1.f / ls[r];
#pragma unroll
    for (int n = 0; n < 4; n++) {
#pragma unroll
      for (int r = 0; r < 4; r++)
        ob[obase + (size_t)(qr0 + rq + r) * 384 + n * 16 + fr] = f2bf(oc[n][r] * inv[r]);
    }
  }
}

// ---------------- orchestration ---------------------------------------------
extern "C" void kernel_launch(void* const* d_in, const int* in_sizes, int n_in,
                              void* d_out, int out_size, void* d_ws, size_t ws_size,
                              hipStream_t stream) {
  const float* x   = (const float*)d_in[0];
  const float* Wq  = (const float*)d_in[1];
  const float* Wk  = (const float*)d_in[2];
  const float* Wv  = (const float*)d_in[3];
  const float* Wo  = (const float*)d_in[4];
  const float* bo  = (const float*)d_in[5];
  const float* W1  = (const float*)d_in[6];
  const float* b1  = (const float*)d_in[7];
  const float* W2  = (const float*)d_in[8];
  const float* b2  = (const float*)d_in[9];
  const float* g1  = (const float*)d_in[10];
  const float* be1 = (const float*)d_in[11];
  const float* g2  = (const float*)d_in[12];
  const float* be2 = (const float*)d_in[13];
  float* out = (float*)d_out;
  char* ws = (char*)d_ws;

  bfu* wqkvT = (bfu*)(ws + 0);          // 1152x384 bf16
  bfu* woT   = (bfu*)(ws + 884736);
  f8u* w1T   = (f8u*)(ws + 1179648);    // 1536x384 fp8
  f8u* w2T   = (f8u*)(ws + 2359296);    // 384x1536 fp8
  char* H    = ws + 3538944;            // h2 (fp8, 25MB)
  char* BIG  = H + 50331648;            // 201.3 MB
  bfu* hb    = (bfu*)BIG;
  bfu* qkvb  = (bfu*)(BIG + 50331648);
  bfu* attnb = (bfu*)BIG;
  f8u* h2b   = (f8u*)H;
  f8u* ab    = (f8u*)BIG;               // 65536x1536 fp8 (100.7MB)

  // 1) weight prep (one launch)
  transpose_all<<<6912, 256, 0, stream>>>(Wq, Wk, Wv, Wo, W1, W2, wqkvT, woT, w1T, w2T);

  // 2) LN1
  ln_kernel<<<16384, 256, 0, stream>>>(x, g1, be1, hb);

  // 3) fused QKV GEMM (N=1152, bf16): 256 x 9 tiles of 256x128
  gemm3b<0, 0, 0, 1><<<2304, 512, 0, stream>>>(hb, wqkvT, nullptr, nullptr, qkvb, 1152, 384, 9);

  // 4) fused causal attention
  attn_kernel<<<1536, 512, 0, stream>>>(qkvb, attnb);

  // 5) proj + bias + residual(x) + LN2 fused -> h2 (fp8)
  row_gemm<<<512, 512, 0, stream>>>(attnb, woT, bo, x, g2, be2, h2b, 384);

  // 6) FFN1 fp8 (+bias+ReLU) -> ab fp8: 256 x 12 tiles of 256x128
  gemm3f8<1, 1, 0, 1><<<3072, 512, 0, stream>>>(h2b, w1T, b1, nullptr, ab, 1536, 384, 12);

  // 7) FFN2 fp8 + bias + residual(x) -> out (fp32): 256 x 3 tiles of 256x128
  gemm3f8<1, 0, 1, 0><<<768, 512, 0, stream>>>(ab, w2T, b2, x, out, 384, 1536, 3);
}

// Round 12
// 525.147 us; speedup vs baseline: 1.3340x; 1.3340x over previous
//
#include <hip/hip_runtime.h>
#include <hip/hip_bf16.h>
#include <hip/hip_fp8.h>

typedef unsigned short bfu;
typedef unsigned char f8u;
typedef __attribute__((ext_vector_type(8))) short short8;
typedef __attribute__((ext_vector_type(4))) float f32x4;

__device__ __forceinline__ bfu f2bf(float f) {
  return __builtin_bit_cast(bfu, __float2bfloat16(f));
}
__device__ __forceinline__ f8u f2f8(float f) {
  __hip_fp8_e4m3 t(f);
  return t.__x;
}

__device__ __forceinline__ void gld16(const void* g, void* l) {
  __builtin_amdgcn_global_load_lds(
      (const __attribute__((address_space(1))) void*)g,
      (__attribute__((address_space(3))) void*)l, 16, 0, 0);
}

// ---- swizzle for 128B rows, 8 x 16B slots per row: phys = slot ^ (row&7)
__device__ __forceinline__ int swz8(int row, int sl) {
  return (row << 7) + (((sl ^ (row & 7)) & 7) << 4);
}

// ---- swizzle for [rows][32]-bf16 tiles (64B rows) used by row_gemm --------
__device__ __forceinline__ int swz(int row, int slot) {
  const int unit = row >> 1;
  const int s8 = ((row & 1) << 2) | slot;
  return (unit << 7) + (((s8 ^ unit) & 7) << 4) + ((s8 >> 3) << 7);
}
__device__ __forceinline__ void unswz(int p, int& row, int& colel) {
  const int unit = p >> 7;
  const int s8 = ((p >> 4) & 7) ^ (unit & 7);
  row = (unit << 1) | (s8 >> 2);
  colel = (s8 & 3) << 3;
}

// ---------------- weight prep in ONE launch ---------------------------------
__global__ void transpose_all(const float* __restrict__ Wq, const float* __restrict__ Wk,
                              const float* __restrict__ Wv, const float* __restrict__ Wo,
                              const float* __restrict__ W1, const float* __restrict__ W2,
                              bfu* __restrict__ wqkvT, bfu* __restrict__ woT,
                              f8u* __restrict__ w1T, f8u* __restrict__ w2T) {
  int idx = blockIdx.x * 256 + threadIdx.x;
  if (idx < 4 * 147456) {
    int r = idx / 147456, i = idx - r * 147456;
    int k = i / 384, n = i - k * 384;
    const float* W = r == 0 ? Wq : r == 1 ? Wk : r == 2 ? Wv : Wo;
    bfu* dst = r < 3 ? wqkvT + r * 147456 : woT;
    dst[n * 384 + k] = f2bf(W[i]);
  } else if (idx < 4 * 147456 + 589824) {
    int i = idx - 4 * 147456;                    // W1: [384][1536]
    int k = i / 1536, n = i - k * 1536;
    w1T[n * 384 + k] = f2f8(W1[i]);
  } else if (idx < 4 * 147456 + 2 * 589824) {
    int i = idx - 4 * 147456 - 589824;           // W2: [1536][384]
    int k = i / 384, n = i - k * 384;
    w2T[(size_t)n * 1536 + k] = f2f8(W2[i]);
  }
}

// ---------------- LayerNorm: one wave per row of 384 ------------------------
__launch_bounds__(256)
__global__ void ln_kernel(const float* __restrict__ in, const float* __restrict__ g,
                          const float* __restrict__ be, bfu* __restrict__ out) {
  const int wv = threadIdx.x >> 6, ln = threadIdx.x & 63;
  const size_t row = (size_t)blockIdx.x * 4 + wv;
  const float* p = in + row * 384;
  float v[6], s = 0.f, ss = 0.f;
#pragma unroll
  for (int i = 0; i < 6; i++) { v[i] = p[i * 64 + ln]; s += v[i]; ss += v[i] * v[i]; }
#pragma unroll
  for (int m = 1; m < 64; m <<= 1) { s += __shfl_xor(s, m); ss += __shfl_xor(ss, m); }
  const float mean = s * (1.f / 384.f);
  const float rs = rsqrtf(ss * (1.f / 384.f) - mean * mean + 1e-5f);
  bfu* q = out + row * 384;
#pragma unroll
  for (int i = 0; i < 6; i++) {
    const int c = i * 64 + ln;
    q[c] = f2bf((v[i] - mean) * rs * g[c] + be[c]);
  }
}

// ---------------- counted-vmcnt GEMM, bf16 (QKV) ----------------------------
template <int BIAS, int RELU, int RES, int OUTBF>
__launch_bounds__(512)
__global__ void gemm3b(const bfu* __restrict__ A, const bfu* __restrict__ Bt,
                       const float* __restrict__ bias, const float* __restrict__ res,
                       void* __restrict__ Cout, int N, int K, int ntn) {
  __shared__ char sm[3 * 49152];
  const int tid = threadIdx.x;
  const int wv = tid >> 6, ln = tid & 63;
  const int cpx = gridDim.x >> 3;
  const int wg = (blockIdx.x & 7) * cpx + (blockIdx.x >> 3);
  const int bm = wg / ntn, bn = wg - bm * ntn;
  const int m0 = bm << 8, n0 = bn << 7;
  const int wr = wv >> 2, wc = wv & 3;
  const int fr = ln & 15, fslot = ln >> 4;
  const int lr = ln >> 3, lsl = (ln & 7) ^ lr;

  f32x4 acc[8][2];
#pragma unroll
  for (int i = 0; i < 8; i++)
#pragma unroll
    for (int j = 0; j < 2; j++) acc[i][j] = f32x4{0.f, 0.f, 0.f, 0.f};

  auto stageA = [&](int dbuf, int kt, int half) {
    char* smA = sm + dbuf * 49152;
    const int col = (kt << 6) + (lsl << 3);
#pragma unroll
    for (int i = 0; i < 2; ++i) {
      const int c = (wv << 2) + (half << 1) + i;
      gld16(A + (size_t)(m0 + (c << 3) + lr) * K + col, smA + (c << 10));
    }
  };
  auto stageB = [&](int dbuf, int kt, int j) {
    char* smB = sm + dbuf * 49152 + 32768;
    const int col = (kt << 6) + (lsl << 3);
    const int c = (wv << 1) + j;
    gld16(Bt + (size_t)(n0 + (c << 3) + lr) * K + col, smB + (c << 10));
  };

  const int nk = K >> 6;
  stageA(0, 0, 0); stageA(0, 0, 1); stageB(0, 0, 0); stageB(0, 0, 1);
  stageA(1, 1, 0); stageA(1, 1, 1); stageB(1, 1, 0); stageB(1, 1, 1);
  asm volatile("s_waitcnt vmcnt(6)" ::: "memory");
  __builtin_amdgcn_s_barrier();

  int cb = 0;
  for (int k = 0; k < nk; ++k) {
    const char* smA = sm + cb * 49152;
    const char* smB = smA + 32768;
    int sb = cb + 2; if (sb >= 3) sb -= 3;
    const bool st = (k + 2) < nk;
#pragma unroll
    for (int mh = 0; mh < 2; ++mh) {
      short8 af[4][2];
#pragma unroll
      for (int i = 0; i < 4; ++i)
#pragma unroll
        for (int ks = 0; ks < 2; ++ks)
          af[i][ks] = *(const short8*)(smA +
              swz8(wr * 128 + mh * 64 + i * 16 + fr, ks * 4 + fslot));
#pragma unroll
      for (int nh = 0; nh < 2; ++nh) {
        short8 bf[2];
#pragma unroll
        for (int ks = 0; ks < 2; ++ks)
          bf[ks] = *(const short8*)(smB + swz8(wc * 32 + nh * 16 + fr, ks * 4 + fslot));
        if (st) {
          if (mh == 0 && nh == 0) stageA(sb, k + 2, 0);
          if (mh == 0 && nh == 1) stageA(sb, k + 2, 1);
          if (mh == 1 && nh == 0) stageB(sb, k + 2, 0);
          if (mh == 1 && nh == 1) stageB(sb, k + 2, 1);
        }
        __builtin_amdgcn_s_barrier();
        asm volatile("s_waitcnt lgkmcnt(0)" ::: "memory");
        __builtin_amdgcn_sched_barrier(0);
        __builtin_amdgcn_s_setprio(1);
#pragma unroll
        for (int i = 0; i < 4; ++i)
#pragma unroll
          for (int ks = 0; ks < 2; ++ks)
            acc[mh * 4 + i][nh] = __builtin_amdgcn_mfma_f32_16x16x32_bf16(
                af[i][ks], bf[ks], acc[mh * 4 + i][nh], 0, 0, 0);
        __builtin_amdgcn_s_setprio(0);
        if (mh == 1 && nh == 1 && k + 1 < nk) {
          if (st) asm volatile("s_waitcnt vmcnt(6)" ::: "memory");
          else    asm volatile("s_waitcnt vmcnt(0)" ::: "memory");
        }
        __builtin_amdgcn_s_barrier();
      }
    }
    cb = (cb + 1 == 3) ? 0 : cb + 1;
  }

  const int rq = (ln >> 4) << 2;
#pragma unroll
  for (int mi = 0; mi < 8; mi++) {
#pragma unroll
    for (int ni = 0; ni < 2; ni++) {
      const int row = m0 + wr * 128 + mi * 16 + rq;
      const int col = n0 + wc * 32 + ni * 16 + fr;
      float bv = 0.f;
      if (BIAS) bv = bias[col];
#pragma unroll
      for (int r = 0; r < 4; r++) {
        float v = acc[mi][ni][r] + bv;
        if (RELU) v = fmaxf(v, 0.f);
        const size_t idx = (size_t)(row + r) * N + col;
        if (RES) v += res[idx];
        if (OUTBF) ((bfu*)Cout)[idx] = f2bf(v);
        else       ((float*)Cout)[idx] = v;
      }
    }
  }
}

// ---------------- counted-vmcnt GEMM, fp8-e4m3, BK=128 ----------------------
// BM=256, BN=128, BK=128 (128B LDS rows == proven bf16 geometry), swz8
// swizzle both sides. 3 bufs x 48KB; 6 loads/K-tile/wave spread [2,2,1,1];
// vmcnt(6) at group tails. 64 MFMA (fp8 K=32) per K-tile per wave.
template <int BIAS, int RELU, int RES, int OUTF8>
__launch_bounds__(512)
__global__ void gemm3f8(const f8u* __restrict__ A, const f8u* __restrict__ Bt,
                        const float* __restrict__ bias, const float* __restrict__ res,
                        void* __restrict__ Cout, int N, int K, int ntn) {
  __shared__ char sm[3 * 49152];    // per buf: A[256][128B]=32KB + B[128][128B]=16KB
  const int tid = threadIdx.x;
  const int wv = tid >> 6, ln = tid & 63;
  const int cpx = gridDim.x >> 3;   // grid % 8 == 0 at all call sites
  const int wg = (blockIdx.x & 7) * cpx + (blockIdx.x >> 3);
  const int bm = wg / ntn, bn = wg - bm * ntn;
  const int m0 = bm << 8, n0 = bn << 7;
  const int wr = wv >> 2, wc = wv & 3;   // wave tile 128x32
  const int fr = ln & 15, fslot = ln >> 4;     // fslot 0..3
  const int s16 = fslot >> 1, off8 = (fslot & 1) << 3;
  const int lr = ln >> 3, lsl = (ln & 7) ^ lr;

  f32x4 acc[8][2];
#pragma unroll
  for (int i = 0; i < 8; i++)
#pragma unroll
    for (int j = 0; j < 2; j++) acc[i][j] = f32x4{0.f, 0.f, 0.f, 0.f};

  auto stageA = [&](int dbuf, int kt, int half) {  // 2 loads: A chunks
    char* smA = sm + dbuf * 49152;
    const int col = (kt << 7) + (lsl << 4);
#pragma unroll
    for (int i = 0; i < 2; ++i) {
      const int c = (wv << 2) + (half << 1) + i;   // 0..31
      gld16(A + (size_t)(m0 + (c << 3) + lr) * K + col, smA + (c << 10));
    }
  };
  auto stageB = [&](int dbuf, int kt, int j) {     // 1 load: B chunk
    char* smB = sm + dbuf * 49152 + 32768;
    const int col = (kt << 7) + (lsl << 4);
    const int c = (wv << 1) + j;                   // 0..15
    gld16(Bt + (size_t)(n0 + (c << 3) + lr) * K + col, smB + (c << 10));
  };

  const int nk = K >> 7;   // K-tiles of 128 (K=384 -> 3, K=1536 -> 12)
  stageA(0, 0, 0); stageA(0, 0, 1); stageB(0, 0, 0); stageB(0, 0, 1);
  stageA(1, 1, 0); stageA(1, 1, 1); stageB(1, 1, 0); stageB(1, 1, 1);
  asm volatile("s_waitcnt vmcnt(6)" ::: "memory");  // K-tile 0 ready; 1 in flight
  __builtin_amdgcn_s_barrier();

  int cb = 0;
  for (int k = 0; k < nk; ++k) {
    const char* smA = sm + cb * 49152;
    const char* smB = smA + 32768;
    int sb = cb + 2; if (sb >= 3) sb -= 3;
    const bool st = (k + 2) < nk;
#pragma unroll
    for (int mh = 0; mh < 2; ++mh) {
      long af[4][4];
#pragma unroll
      for (int i = 0; i < 4; ++i)
#pragma unroll
        for (int ks = 0; ks < 4; ++ks)
          af[i][ks] = *(const long*)(smA +
              swz8(wr * 128 + mh * 64 + i * 16 + fr, ks * 2 + s16) + off8);
#pragma unroll
      for (int nh = 0; nh < 2; ++nh) {
        long bf[4];
#pragma unroll
        for (int ks = 0; ks < 4; ++ks)
          bf[ks] = *(const long*)(smB +
              swz8(wc * 32 + nh * 16 + fr, ks * 2 + s16) + off8);
        if (st) {
          if (mh == 0 && nh == 0) stageA(sb, k + 2, 0);
          if (mh == 0 && nh == 1) stageA(sb, k + 2, 1);
          if (mh == 1 && nh == 0) stageB(sb, k + 2, 0);
          if (mh == 1 && nh == 1) stageB(sb, k + 2, 1);
        }
        __builtin_amdgcn_s_barrier();
        asm volatile("s_waitcnt lgkmcnt(0)" ::: "memory");
        __builtin_amdgcn_sched_barrier(0);
        __builtin_amdgcn_s_setprio(1);
#pragma unroll
        for (int ks = 0; ks < 4; ++ks)
#pragma unroll
          for (int i = 0; i < 4; ++i)
            acc[mh * 4 + i][nh] = __builtin_amdgcn_mfma_f32_16x16x32_fp8_fp8(
                af[i][ks], bf[ks], acc[mh * 4 + i][nh], 0, 0, 0);
        __builtin_amdgcn_s_setprio(0);
        if (mh == 1 && nh == 1 && k + 1 < nk) {
          if (st) asm volatile("s_waitcnt vmcnt(6)" ::: "memory");
          else    asm volatile("s_waitcnt vmcnt(0)" ::: "memory");
        }
        __builtin_amdgcn_s_barrier();
      }
    }
    cb = (cb + 1 == 3) ? 0 : cb + 1;
  }

  const int rq = (ln >> 4) << 2;
#pragma unroll
  for (int mi = 0; mi < 8; mi++) {
#pragma unroll
    for (int ni = 0; ni < 2; ni++) {
      const int row = m0 + wr * 128 + mi * 16 + rq;
      const int col = n0 + wc * 32 + ni * 16 + fr;
      float bv = 0.f;
      if (BIAS) bv = bias[col];
#pragma unroll
      for (int r = 0; r < 4; r++) {
        float v = acc[mi][ni][r] + bv;
        if (RELU) v = fmaxf(v, 0.f);
        const size_t idx = (size_t)(row + r) * N + col;
        if (RES) v += res[idx];
        if (OUTF8) ((f8u*)Cout)[idx] = f2f8(v);
        else       ((float*)Cout)[idx] = v;
      }
    }
  }
}

// ---------------- full-row GEMM (proj + LN2 fusion): C[M,384] ---------------
// Output h2 as fp8-e4m3 (feeds fp8 FFN1).
__launch_bounds__(512)
__global__ void row_gemm(const bfu* __restrict__ A, const bfu* __restrict__ Bt,
                         const float* __restrict__ bias, const float* __restrict__ res,
                         const float* __restrict__ g, const float* __restrict__ be,
                         f8u* __restrict__ Cout, int K) {
  __shared__ bfu a_sm[4][128 * 32];
  __shared__ bfu b_sm[4][384 * 32];
  __shared__ float lnp[4][128][2];
  const int tid = threadIdx.x;
  const int wv = tid >> 6, ln = tid & 63;
  const int wr = wv >> 2, wc = wv & 3;
  const int fr = ln & 15, fslot = ln >> 4;
  const int m0 = blockIdx.x << 7;

  f32x4 acc[4][6];
#pragma unroll
  for (int i = 0; i < 4; i++)
#pragma unroll
    for (int j = 0; j < 6; j++) acc[i][j] = f32x4{0.f, 0.f, 0.f, 0.f};

  auto stage = [&](int buf, int kt) {
#pragma unroll
    for (int i = 0; i < 4; ++i) {
      const int c = wv * 4 + i;
      const int cc = (c < 8) ? c : (c - 8);
      const int p = cc * 1024 + (ln << 4);
      int r, colel;
      unswz(p, r, colel);
      const int col = kt * 32 + colel;
      if (c < 8)
        gld16(A + (size_t)(m0 + r) * K + col, (char*)a_sm[buf] + cc * 1024);
      else
        gld16(Bt + (size_t)r * K + col, (char*)b_sm[buf] + cc * 1024);
    }
  };

  const int nk = K >> 5;
#pragma unroll
  for (int i = 0; i < 3; ++i)
    if (i < nk) stage(i, i);

  for (int kt = 0; kt < nk; ++kt) {
    const int rem = nk - 1 - kt;
    if (rem >= 2)      asm volatile("s_waitcnt vmcnt(8)" ::: "memory");
    else if (rem == 1) asm volatile("s_waitcnt vmcnt(4)" ::: "memory");
    else               asm volatile("s_waitcnt vmcnt(0)" ::: "memory");
    __builtin_amdgcn_s_barrier();
    __builtin_amdgcn_sched_barrier(0);
    if (kt + 3 < nk) stage((kt + 3) & 3, kt + 3);
    const int cb = kt & 3;
    short8 af[4], bfr[6];
#pragma unroll
    for (int mi = 0; mi < 4; mi++)
      af[mi] = *(const short8*)((const char*)a_sm[cb] + swz(wr * 64 + mi * 16 + fr, fslot));
#pragma unroll
    for (int ni = 0; ni < 6; ni++)
      bfr[ni] = *(const short8*)((const char*)b_sm[cb] + swz(wc * 96 + ni * 16 + fr, fslot));
    __builtin_amdgcn_s_setprio(1);
#pragma unroll
    for (int mi = 0; mi < 4; mi++)
#pragma unroll
      for (int ni = 0; ni < 6; ni++)
        acc[mi][ni] = __builtin_amdgcn_mfma_f32_16x16x32_bf16(af[mi], bfr[ni], acc[mi][ni], 0, 0, 0);
    __builtin_amdgcn_s_setprio(0);
  }

  const int rq = (ln >> 4) << 2;
#pragma unroll
  for (int mi = 0; mi < 4; mi++) {
    const int row = wr * 64 + mi * 16 + rq;
#pragma unroll
    for (int ni = 0; ni < 6; ni++) {
      const int col = wc * 96 + ni * 16 + fr;
      const float bv = bias[col];
#pragma unroll
      for (int r = 0; r < 4; r++)
        acc[mi][ni][r] += bv + res[(size_t)(m0 + row + r) * 384 + col];
    }
  }

#pragma unroll
  for (int mi = 0; mi < 4; mi++) {
    float s[4] = {0.f, 0.f, 0.f, 0.f}, ss[4] = {0.f, 0.f, 0.f, 0.f};
#pragma unroll
    for (int ni = 0; ni < 6; ni++)
#pragma unroll
      for (int r = 0; r < 4; r++) {
        const float v = acc[mi][ni][r];
        s[r] += v; ss[r] += v * v;
      }
#pragma unroll
    for (int m = 1; m < 16; m <<= 1)
#pragma unroll
      for (int r = 0; r < 4; r++) {
        s[r] += __shfl_xor(s[r], m);
        ss[r] += __shfl_xor(ss[r], m);
      }
    if (fr == 0) {
#pragma unroll
      for (int r = 0; r < 4; r++) {
        lnp[wc][wr * 64 + mi * 16 + rq + r][0] = s[r];
        lnp[wc][wr * 64 + mi * 16 + rq + r][1] = ss[r];
      }
    }
  }
  __syncthreads();
#pragma unroll
  for (int mi = 0; mi < 4; mi++) {
#pragma unroll
    for (int r = 0; r < 4; r++) {
      const int row = wr * 64 + mi * 16 + rq + r;
      const float sm = lnp[0][row][0] + lnp[1][row][0] + lnp[2][row][0] + lnp[3][row][0];
      const float sq = lnp[0][row][1] + lnp[1][row][1] + lnp[2][row][1] + lnp[3][row][1];
      const float mean = sm * (1.f / 384.f);
      const float rs = rsqrtf(sq * (1.f / 384.f) - mean * mean + 1e-5f);
#pragma unroll
      for (int ni = 0; ni < 6; ni++) {
        const int col = wc * 96 + ni * 16 + fr;
        Cout[(size_t)(m0 + row) * 384 + col] =
            f2f8((acc[mi][ni][r] - mean) * rs * g[col] + be[col]);
      }
    }
  }
}

// ---------------- fused causal attention: 1 block per (b,h), 8 waves --------
#define KPAD 72
#define VPAD 264
#define PPAD 264

__launch_bounds__(512)
__global__ void attn_kernel(const bfu* __restrict__ qkv, bfu* __restrict__ ob) {
  __shared__ bfu k_sm[256 * KPAD];
  __shared__ bfu vt_sm[64 * VPAD];
  __shared__ bfu p_sm[8 * 16 * PPAD];
  const int b = blockIdx.x / 6, h = blockIdx.x - b * 6;
  const int tid = threadIdx.x;
  const int wv = tid >> 6, ln = tid & 63;
  const int fr = ln & 15, fc = (ln >> 4) << 3;
  const size_t inbase = (size_t)b * 256 * 1152 + h * 64;
  const bfu* qb = qkv + inbase;
  const bfu* kb = qkv + inbase + 384;
  const bfu* vb = qkv + inbase + 768;
  const size_t obase = (size_t)b * 256 * 384 + h * 64;

  {
    const int row = tid >> 1;
    const int dh = (tid & 1) << 5;
    const bfu* kg = kb + (size_t)row * 1152 + dh;
    const bfu* vg = vb + (size_t)row * 1152 + dh;
#pragma unroll
    for (int i = 0; i < 4; i++) {
      short8 t8 = *(const short8*)(kg + i * 8);
      *(short8*)&k_sm[row * KPAD + dh + i * 8] = t8;
      short8 v8 = *(const short8*)(vg + i * 8);
#pragma unroll
      for (int j = 0; j < 8; j++)
        vt_sm[(dh + i * 8 + j) * VPAD + row] = (bfu)v8[j];
    }
  }
  __syncthreads();

  bfu* pw = &p_sm[wv * 16 * PPAD];
  const int rq = (ln >> 4) << 2;

#pragma unroll
  for (int si = 0; si < 2; ++si) {
    const int s = si ? (15 - wv) : wv;
    const int qr0 = s << 4;
    const int nf = s + 1;
    short8 aq[2];
#pragma unroll
    for (int dc = 0; dc < 2; dc++)
      aq[dc] = *(const short8*)(qb + (size_t)(qr0 + fr) * 1152 + dc * 32 + fc);

    f32x4 sacc[16];
#pragma unroll
    for (int f = 0; f < 16; f++) sacc[f] = f32x4{0.f, 0.f, 0.f, 0.f};
#pragma unroll
    for (int f = 0; f < 16; f++) if (f < nf) {
#pragma unroll
      for (int dc = 0; dc < 2; dc++) {
        short8 kf = *(const short8*)&k_sm[(f * 16 + fr) * KPAD + dc * 32 + fc];
        sacc[f] = __builtin_amdgcn_mfma_f32_16x16x32_bf16(aq[dc], kf, sacc[f], 0, 0, 0);
      }
    }
    float mr[4] = {-3e38f, -3e38f, -3e38f, -3e38f};
#pragma unroll
    for (int f = 0; f < 16; f++) if (f < nf) {
#pragma unroll
      for (int r = 0; r < 4; r++) {
        float sv = sacc[f][r] * 0.125f;
        if (f * 16 + fr > qr0 + rq + r) sv = -3e38f;
        sacc[f][r] = sv;
        mr[r] = fmaxf(mr[r], sv);
      }
    }
#pragma unroll
    for (int msk = 1; msk < 16; msk <<= 1) {
#pragma unroll
      for (int r = 0; r < 4; r++) mr[r] = fmaxf(mr[r], __shfl_xor(mr[r], msk));
    }
    float ls[4] = {0.f, 0.f, 0.f, 0.f};
#pragma unroll
    for (int f = 0; f < 16; f++) if (f < nf) {
#pragma unroll
      for (int r = 0; r < 4; r++) {
        float p = __expf(sacc[f][r] - mr[r]);
        sacc[f][r] = p;
        ls[r] += p;
      }
    }
#pragma unroll
    for (int msk = 1; msk < 16; msk <<= 1) {
#pragma unroll
      for (int r = 0; r < 4; r++) ls[r] += __shfl_xor(ls[r], msk);
    }
#pragma unroll
    for (int f = 0; f < 16; f++) if (f < nf) {
#pragma unroll
      for (int r = 0; r < 4; r++)
        pw[(rq + r) * PPAD + f * 16 + fr] = f2bf(sacc[f][r]);
    }
    if (nf & 1) {
#pragma unroll
      for (int r = 0; r < 4; r++) pw[(rq + r) * PPAD + nf * 16 + fr] = 0;
    }
    f32x4 oc[4];
#pragma unroll
    for (int n = 0; n < 4; n++) oc[n] = f32x4{0.f, 0.f, 0.f, 0.f};
    const int kcs = (nf + 1) >> 1;
#pragma unroll
    for (int kc = 0; kc < 8; ++kc) if (kc < kcs) {
      short8 pa = *(const short8*)&pw[fr * PPAD + kc * 32 + fc];
#pragma unroll
      for (int n = 0; n < 4; n++) {
        short8 vf = *(const short8*)&vt_sm[(n * 16 + fr) * VPAD + kc * 32 + fc];
        oc[n] = __builtin_amdgcn_mfma_f32_16x16x32_bf16(pa, vf, oc[n], 0, 0, 0);
      }
    }
    float inv[4];
#pragma unroll
    for (int r = 0; r < 4; r++) inv[r] = 1.f / ls[r];
#pragma unroll
    for (int n = 0; n < 4; n++) {
#pragma unroll
      for (int r = 0; r < 4; r++)
        ob[obase + (size_t)(qr0 + rq + r) * 384 + n * 16 + fr] = f2bf(oc[n][r] * inv[r]);
    }
  }
}

// ---------------- orchestration ---------------------------------------------
extern "C" void kernel_launch(void* const* d_in, const int* in_sizes, int n_in,
                              void* d_out, int out_size, void* d_ws, size_t ws_size,
                              hipStream_t stream) {
  const float* x   = (const float*)d_in[0];
  const float* Wq  = (const float*)d_in[1];
  const float* Wk  = (const float*)d_in[2];
  const float* Wv  = (const float*)d_in[3];
  const float* Wo  = (const float*)d_in[4];
  const float* bo  = (const float*)d_in[5];
  const float* W1  = (const float*)d_in[6];
  const float* b1  = (const float*)d_in[7];
  const float* W2  = (const float*)d_in[8];
  const float* b2  = (const float*)d_in[9];
  const float* g1  = (const float*)d_in[10];
  const float* be1 = (const float*)d_in[11];
  const float* g2  = (const float*)d_in[12];
  const float* be2 = (const float*)d_in[13];
  float* out = (float*)d_out;
  char* ws = (char*)d_ws;

  bfu* wqkvT = (bfu*)(ws + 0);          // 1152x384 bf16
  bfu* woT   = (bfu*)(ws + 884736);
  f8u* w1T   = (f8u*)(ws + 1179648);    // 1536x384 fp8
  f8u* w2T   = (f8u*)(ws + 2359296);    // 384x1536 fp8
  char* H    = ws + 3538944;            // h2 (fp8, 25MB)
  char* BIG  = H + 50331648;            // 201.3 MB
  bfu* hb    = (bfu*)BIG;
  bfu* qkvb  = (bfu*)(BIG + 50331648);
  bfu* attnb = (bfu*)BIG;
  f8u* h2b   = (f8u*)H;
  f8u* ab    = (f8u*)BIG;               // 65536x1536 fp8 (100.7MB)

  // 1) weight prep (one launch)
  transpose_all<<<6912, 256, 0, stream>>>(Wq, Wk, Wv, Wo, W1, W2, wqkvT, woT, w1T, w2T);

  // 2) LN1
  ln_kernel<<<16384, 256, 0, stream>>>(x, g1, be1, hb);

  // 3) fused QKV GEMM (N=1152, bf16): 256 x 9 tiles of 256x128
  gemm3b<0, 0, 0, 1><<<2304, 512, 0, stream>>>(hb, wqkvT, nullptr, nullptr, qkvb, 1152, 384, 9);

  // 4) fused causal attention
  attn_kernel<<<1536, 512, 0, stream>>>(qkvb, attnb);

  // 5) proj + bias + residual(x) + LN2 fused -> h2 (fp8)
  row_gemm<<<512, 512, 0, stream>>>(attnb, woT, bo, x, g2, be2, h2b, 384);

  // 6) FFN1 fp8 (+bias+ReLU) -> ab fp8: 256 x 12 tiles of 256x128
  gemm3f8<1, 1, 0, 1><<<3072, 512, 0, stream>>>(h2b, w1T, b1, nullptr, ab, 1536, 384, 12);

  // 7) FFN2 fp8 + bias + residual(x) -> out (fp32): 256 x 3 tiles of 256x128
  gemm3f8<1, 0, 1, 0><<<768, 512, 0, stream>>>(ab, w2T, b2, x, out, 384, 1536, 3);
}

// Round 13
// 477.904 us; speedup vs baseline: 1.4659x; 1.0989x over previous
//
#include <hip/hip_runtime.h>
#include <hip/hip_bf16.h>

typedef unsigned short bfu;
typedef __attribute__((ext_vector_type(8))) short short8;
typedef __attribute__((ext_vector_type(4))) float f32x4;

__device__ __forceinline__ bfu f2bf(float f) {
  return __builtin_bit_cast(bfu, __float2bfloat16(f));
}

__device__ __forceinline__ void gld16(const void* g, void* l) {
  __builtin_amdgcn_global_load_lds(
      (const __attribute__((address_space(1))) void*)g,
      (__attribute__((address_space(3))) void*)l, 16, 0, 0);
}

// ---- swizzle for [rows][64]-bf16 tiles (128B rows, 8 x 16B slots per row)
__device__ __forceinline__ int swz8(int row, int sl) {
  return (row << 7) + (((sl ^ (row & 7)) & 7) << 4);
}

// ---- swizzle for [rows][32]-bf16 tiles (64B rows) used by row_gemm --------
__device__ __forceinline__ int swz(int row, int slot) {
  const int unit = row >> 1;
  const int s8 = ((row & 1) << 2) | slot;
  return (unit << 7) + (((s8 ^ unit) & 7) << 4) + ((s8 >> 3) << 7);
}
__device__ __forceinline__ void unswz(int p, int& row, int& colel) {
  const int unit = p >> 7;
  const int s8 = ((p >> 4) & 7) ^ (unit & 7);
  row = (unit << 1) | (s8 >> 2);
  colel = (s8 & 3) << 3;
}

// ---------------- all weight transposes in ONE launch -----------------------
__global__ void transpose_all(const float* __restrict__ Wq, const float* __restrict__ Wk,
                              const float* __restrict__ Wv, const float* __restrict__ Wo,
                              const float* __restrict__ W1, const float* __restrict__ W2,
                              bfu* __restrict__ wqkvT, bfu* __restrict__ woT,
                              bfu* __restrict__ w1T, bfu* __restrict__ w2T) {
  int idx = blockIdx.x * 256 + threadIdx.x;
  if (idx < 4 * 147456) {
    int r = idx / 147456, i = idx - r * 147456;
    int k = i / 384, n = i - k * 384;
    const float* W = r == 0 ? Wq : r == 1 ? Wk : r == 2 ? Wv : Wo;
    bfu* dst = r < 3 ? wqkvT + r * 147456 : woT;
    dst[n * 384 + k] = f2bf(W[i]);
  } else if (idx < 4 * 147456 + 589824) {
    int i = idx - 4 * 147456;                    // W1: [384][1536]
    int k = i / 1536, n = i - k * 1536;
    w1T[n * 384 + k] = f2bf(W1[i]);
  } else if (idx < 4 * 147456 + 2 * 589824) {
    int i = idx - 4 * 147456 - 589824;           // W2: [1536][384]
    int k = i / 384, n = i - k * 384;
    w2T[(size_t)n * 1536 + k] = f2bf(W2[i]);
  }
}

// ---------------- LayerNorm: one wave per row of 384 ------------------------
__launch_bounds__(256)
__global__ void ln_kernel(const float* __restrict__ in, const float* __restrict__ g,
                          const float* __restrict__ be, bfu* __restrict__ out) {
  const int wv = threadIdx.x >> 6, ln = threadIdx.x & 63;
  const size_t row = (size_t)blockIdx.x * 4 + wv;
  const float* p = in + row * 384;
  float v[6], s = 0.f, ss = 0.f;
#pragma unroll
  for (int i = 0; i < 6; i++) { v[i] = p[i * 64 + ln]; s += v[i]; ss += v[i] * v[i]; }
#pragma unroll
  for (int m = 1; m < 64; m <<= 1) { s += __shfl_xor(s, m); ss += __shfl_xor(ss, m); }
  const float mean = s * (1.f / 384.f);
  const float rs = rsqrtf(ss * (1.f / 384.f) - mean * mean + 1e-5f);
  bfu* q = out + row * 384;
#pragma unroll
  for (int i = 0; i < 6; i++) {
    const int c = i * 64 + ln;
    q[c] = f2bf((v[i] - mean) * rs * g[c] + be[c]);
  }
}

// ---------------- fat-tile 4-phase GEMM: C[M,N] = A[M,K] @ Bt[N,K]^T --------
// R7 K-loop (verified). NEW: coalesced epilogue via LDS round-trip — after
// the K-loop the LDS bufs are dead; each wave stages each 16-row C-slice in
// a private padded scratch, reads back linear, stores short8/f32x4 (full
// 256B row segments instead of scattered 2B/4B scalars).
template <int WM, int WN, int BIAS, int RELU, int RES, int OUTBF>
__launch_bounds__(512)
__global__ void gemm_ph(const bfu* __restrict__ A, const bfu* __restrict__ Bt,
                        const float* __restrict__ bias, const float* __restrict__ res,
                        void* __restrict__ Cout, int N, int K, int ntn) {
  constexpr int BM = WM * 32;
  constexpr int BN = WN * 64;
  constexpr int ACH = BM / 64;     // A 1KB-chunks per wave
  constexpr int BCH = BN / 64;     // B 1KB-chunks per wave
  __shared__ bfu sm[2][(BM + BN) * 64];
  const int tid = threadIdx.x;
  const int wv = tid >> 6, ln = tid & 63;
  const int cpx = gridDim.x >> 3;            // grid % 8 == 0 at all call sites
  const int wg = (blockIdx.x & 7) * cpx + (blockIdx.x >> 3);
  const int bm = wg / ntn, bn = wg - bm * ntn;
  const int m0 = bm * BM, n0 = bn * BN;
  const int wr = wv >> 2, wc = wv & 3;       // 2m x 4n wave grid
  const int fr = ln & 15, fslot = ln >> 4;
  const int lr = ln >> 3, lsl = (ln & 7) ^ lr;   // staging row / logical slot

  f32x4 acc[WM][WN];
#pragma unroll
  for (int i = 0; i < WM; i++)
#pragma unroll
    for (int j = 0; j < WN; j++) acc[i][j] = f32x4{0.f, 0.f, 0.f, 0.f};

  auto stageA = [&](int s, int kt) {
    char* smA = (char*)sm[s];
    const int col = (kt << 6) + (lsl << 3);
#pragma unroll
    for (int i = 0; i < ACH; ++i) {
      const int c = wv * ACH + i;
      gld16(A + (size_t)(m0 + (c << 3) + lr) * K + col, smA + (c << 10));
    }
  };
  auto stageB = [&](int s, int kt) {
    char* smB = (char*)sm[s] + BM * 128;
    const int col = (kt << 6) + (lsl << 3);
#pragma unroll
    for (int i = 0; i < BCH; ++i) {
      const int c = wv * BCH + i;
      gld16(Bt + (size_t)(n0 + (c << 3) + lr) * K + col, smB + (c << 10));
    }
  };

  const int nk = K >> 6;
  stageA(0, 0);
  stageB(0, 0);
  asm volatile("s_waitcnt vmcnt(0)" ::: "memory");
  __builtin_amdgcn_s_barrier();

  for (int kt = 0; kt < nk; ++kt) {
    const int cur = kt & 1;
    const char* smA = (const char*)sm[cur];
    const char* smB = smA + BM * 128;
    short8 bf[2][WN];
#pragma unroll
    for (int ph = 0; ph < 4; ++ph) {
      const int mh = ph >> 1, ks = ph & 1;
      short8 af[WM / 2];
#pragma unroll
      for (int i = 0; i < WM / 2; ++i)
        af[i] = *(const short8*)(smA +
            swz8(wr * (WM * 16) + (mh * (WM / 2) + i) * 16 + fr, ks * 4 + fslot));
      if (mh == 0) {
#pragma unroll
        for (int ni = 0; ni < WN; ++ni)
          bf[ks][ni] = *(const short8*)(smB +
              swz8(wc * (WN * 16) + ni * 16 + fr, ks * 4 + fslot));
      }
      if (kt + 1 < nk) {
        if (ph == 0) stageA(cur ^ 1, kt + 1);
        if (ph == 1) stageB(cur ^ 1, kt + 1);
      }
      __builtin_amdgcn_s_barrier();
      asm volatile("s_waitcnt lgkmcnt(0)" ::: "memory");
      __builtin_amdgcn_sched_barrier(0);
      __builtin_amdgcn_s_setprio(1);
#pragma unroll
      for (int i = 0; i < WM / 2; ++i)
#pragma unroll
        for (int ni = 0; ni < WN; ++ni)
          acc[mh * (WM / 2) + i][ni] = __builtin_amdgcn_mfma_f32_16x16x32_bf16(
              af[i], bf[ks][ni], acc[mh * (WM / 2) + i][ni], 0, 0, 0);
      __builtin_amdgcn_s_setprio(0);
      __builtin_amdgcn_s_barrier();
    }
    if (kt + 1 < nk) {
      asm volatile("s_waitcnt vmcnt(0)" ::: "memory");
      __builtin_amdgcn_s_barrier();
    }
  }

  // ---- coalesced epilogue (LDS bufs dead; per-wave private scratch) --------
  const int rq = fslot << 2;
  if (OUTBF) {
    constexpr int SSTR = WN * 16 + 8;                    // shorts per scratch row
    bfu* scr = (bfu*)((char*)sm + wv * (SSTR * 16 * 2));
#pragma unroll
    for (int mi = 0; mi < WM; mi++) {
#pragma unroll
      for (int ni = 0; ni < WN; ni++) {
        const int col = n0 + wc * (WN * 16) + ni * 16 + fr;
        float bv = 0.f;
        if (BIAS) bv = bias[col];
#pragma unroll
        for (int r = 0; r < 4; r++) {
          float v = acc[mi][ni][r] + bv;
          if (RELU) v = fmaxf(v, 0.f);
          scr[(rq + r) * SSTR + ni * 16 + fr] = f2bf(v);
        }
      }
      constexpr int NCH = WN * 2 * 16;                   // 16B chunks (16 rows x WN*2)
#pragma unroll
      for (int f0 = 0; f0 < NCH; f0 += 64) {
        const int f = f0 + ln;
        if (f < NCH) {
          const int row = f / (WN * 2), c16 = f - row * (WN * 2);
          short8 v = *(const short8*)((const char*)scr + row * SSTR * 2 + c16 * 16);
          const int grow = m0 + wr * (WM * 16) + mi * 16 + row;
          const int gcol = n0 + wc * (WN * 16) + c16 * 8;
          *(short8*)((bfu*)Cout + (size_t)grow * N + gcol) = v;
        }
      }
    }
  } else {
    constexpr int SSTR = WN * 16 + 4;                    // floats per scratch row
    float* scr = (float*)((char*)sm + wv * (SSTR * 16 * 4));
#pragma unroll
    for (int mi = 0; mi < WM; mi++) {
#pragma unroll
      for (int ni = 0; ni < WN; ni++) {
#pragma unroll
        for (int r = 0; r < 4; r++)
          scr[(rq + r) * SSTR + ni * 16 + fr] = acc[mi][ni][r];
      }
      constexpr int NCH = WN * 4 * 16;                   // 4-float chunks (16 rows x WN*4)
#pragma unroll
      for (int f0 = 0; f0 < NCH; f0 += 64) {
        const int f = f0 + ln;
        if (f < NCH) {
          const int row = f / (WN * 4), cf = (f - row * (WN * 4)) * 4;
          f32x4 v = *(const f32x4*)(scr + row * SSTR + cf);
          const int grow = m0 + wr * (WM * 16) + mi * 16 + row;
          const int gcol = n0 + wc * (WN * 16) + cf;
          const size_t idx = (size_t)grow * N + gcol;
          if (BIAS) v += *(const f32x4*)(bias + gcol);
          if (RELU) {
#pragma unroll
            for (int e = 0; e < 4; e++) v[e] = fmaxf(v[e], 0.f);
          }
          if (RES) v += *(const f32x4*)(res + idx);
          *(f32x4*)((float*)Cout + idx) = v;
        }
      }
    }
  }
}

// ---------------- full-row GEMM (proj + LN2 fusion): C[M,384] ---------------
__launch_bounds__(512)
__global__ void row_gemm(const bfu* __restrict__ A, const bfu* __restrict__ Bt,
                         const float* __restrict__ bias, const float* __restrict__ res,
                         const float* __restrict__ g, const float* __restrict__ be,
                         void* __restrict__ Cout, int K) {
  __shared__ bfu a_sm[4][128 * 32];
  __shared__ bfu b_sm[4][384 * 32];
  __shared__ float lnp[4][128][2];
  const int tid = threadIdx.x;
  const int wv = tid >> 6, ln = tid & 63;
  const int wr = wv >> 2, wc = wv & 3;
  const int fr = ln & 15, fslot = ln >> 4;
  const int m0 = blockIdx.x << 7;

  f32x4 acc[4][6];
#pragma unroll
  for (int i = 0; i < 4; i++)
#pragma unroll
    for (int j = 0; j < 6; j++) acc[i][j] = f32x4{0.f, 0.f, 0.f, 0.f};

  auto stage = [&](int buf, int kt) {
#pragma unroll
    for (int i = 0; i < 4; ++i) {
      const int c = wv * 4 + i;
      const int cc = (c < 8) ? c : (c - 8);
      const int p = cc * 1024 + (ln << 4);
      int r, colel;
      unswz(p, r, colel);
      const int col = kt * 32 + colel;
      if (c < 8)
        gld16(A + (size_t)(m0 + r) * K + col, (char*)a_sm[buf] + cc * 1024);
      else
        gld16(Bt + (size_t)r * K + col, (char*)b_sm[buf] + cc * 1024);
    }
  };

  const int nk = K >> 5;
#pragma unroll
  for (int i = 0; i < 3; ++i)
    if (i < nk) stage(i, i);

  for (int kt = 0; kt < nk; ++kt) {
    const int rem = nk - 1 - kt;
    if (rem >= 2)      asm volatile("s_waitcnt vmcnt(8)" ::: "memory");
    else if (rem == 1) asm volatile("s_waitcnt vmcnt(4)" ::: "memory");
    else               asm volatile("s_waitcnt vmcnt(0)" ::: "memory");
    __builtin_amdgcn_s_barrier();
    __builtin_amdgcn_sched_barrier(0);
    if (kt + 3 < nk) stage((kt + 3) & 3, kt + 3);
    const int cb = kt & 3;
    short8 af[4], bfr[6];
#pragma unroll
    for (int mi = 0; mi < 4; mi++)
      af[mi] = *(const short8*)((const char*)a_sm[cb] + swz(wr * 64 + mi * 16 + fr, fslot));
#pragma unroll
    for (int ni = 0; ni < 6; ni++)
      bfr[ni] = *(const short8*)((const char*)b_sm[cb] + swz(wc * 96 + ni * 16 + fr, fslot));
    __builtin_amdgcn_s_setprio(1);
#pragma unroll
    for (int mi = 0; mi < 4; mi++)
#pragma unroll
      for (int ni = 0; ni < 6; ni++)
        acc[mi][ni] = __builtin_amdgcn_mfma_f32_16x16x32_bf16(af[mi], bfr[ni], acc[mi][ni], 0, 0, 0);
    __builtin_amdgcn_s_setprio(0);
  }

  const int rq = (ln >> 4) << 2;
#pragma unroll
  for (int mi = 0; mi < 4; mi++) {
    const int row = wr * 64 + mi * 16 + rq;
#pragma unroll
    for (int ni = 0; ni < 6; ni++) {
      const int col = wc * 96 + ni * 16 + fr;
      const float bv = bias[col];
#pragma unroll
      for (int r = 0; r < 4; r++)
        acc[mi][ni][r] += bv + res[(size_t)(m0 + row + r) * 384 + col];
    }
  }

#pragma unroll
  for (int mi = 0; mi < 4; mi++) {
    float s[4] = {0.f, 0.f, 0.f, 0.f}, ss[4] = {0.f, 0.f, 0.f, 0.f};
#pragma unroll
    for (int ni = 0; ni < 6; ni++)
#pragma unroll
      for (int r = 0; r < 4; r++) {
        const float v = acc[mi][ni][r];
        s[r] += v; ss[r] += v * v;
      }
#pragma unroll
    for (int m = 1; m < 16; m <<= 1)
#pragma unroll
      for (int r = 0; r < 4; r++) {
        s[r] += __shfl_xor(s[r], m);
        ss[r] += __shfl_xor(ss[r], m);
      }
    if (fr == 0) {
#pragma unroll
      for (int r = 0; r < 4; r++) {
        lnp[wc][wr * 64 + mi * 16 + rq + r][0] = s[r];
        lnp[wc][wr * 64 + mi * 16 + rq + r][1] = ss[r];
      }
    }
  }
  __syncthreads();
#pragma unroll
  for (int mi = 0; mi < 4; mi++) {
#pragma unroll
    for (int r = 0; r < 4; r++) {
      const int row = wr * 64 + mi * 16 + rq + r;
      const float sm = lnp[0][row][0] + lnp[1][row][0] + lnp[2][row][0] + lnp[3][row][0];
      const float sq = lnp[0][row][1] + lnp[1][row][1] + lnp[2][row][1] + lnp[3][row][1];
      const float mean = sm * (1.f / 384.f);
      const float rs = rsqrtf(sq * (1.f / 384.f) - mean * mean + 1e-5f);
#pragma unroll
      for (int ni = 0; ni < 6; ni++) {
        const int col = wc * 96 + ni * 16 + fr;
        ((bfu*)Cout)[(size_t)(m0 + row) * 384 + col] =
            f2bf((acc[mi][ni][r] - mean) * rs * g[col] + be[col]);
      }
    }
  }
}

// ---------------- fused causal attention: 1 block per (b,h), 8 waves --------
#define KPAD 72
#define VPAD 264
#define PPAD 264

__launch_bounds__(512)
__global__ void attn_kernel(const bfu* __restrict__ qkv, bfu* __restrict__ ob) {
  __shared__ bfu k_sm[256 * KPAD];
  __shared__ bfu vt_sm[64 * VPAD];
  __shared__ bfu p_sm[8 * 16 * PPAD];
  const int b = blockIdx.x / 6, h = blockIdx.x - b * 6;
  const int tid = threadIdx.x;
  const int wv = tid >> 6, ln = tid & 63;
  const int fr = ln & 15, fc = (ln >> 4) << 3;
  const size_t inbase = (size_t)b * 256 * 1152 + h * 64;
  const bfu* qb = qkv + inbase;
  const bfu* kb = qkv + inbase + 384;
  const bfu* vb = qkv + inbase + 768;
  const size_t obase = (size_t)b * 256 * 384 + h * 64;

  {
    const int row = tid >> 1;
    const int dh = (tid & 1) << 5;
    const bfu* kg = kb + (size_t)row * 1152 + dh;
    const bfu* vg = vb + (size_t)row * 1152 + dh;
#pragma unroll
    for (int i = 0; i < 4; i++) {
      short8 t8 = *(const short8*)(kg + i * 8);
      *(short8*)&k_sm[row * KPAD + dh + i * 8] = t8;
      short8 v8 = *(const short8*)(vg + i * 8);
#pragma unroll
      for (int j = 0; j < 8; j++)
        vt_sm[(dh + i * 8 + j) * VPAD + row] = (bfu)v8[j];
    }
  }
  __syncthreads();

  bfu* pw = &p_sm[wv * 16 * PPAD];
  const int rq = (ln >> 4) << 2;

#pragma unroll
  for (int si = 0; si < 2; ++si) {
    const int s = si ? (15 - wv) : wv;
    const int qr0 = s << 4;
    const int nf = s + 1;
    short8 aq[2];
#pragma unroll
    for (int dc = 0; dc < 2; dc++)
      aq[dc] = *(const short8*)(qb + (size_t)(qr0 + fr) * 1152 + dc * 32 + fc);

    f32x4 sacc[16];
#pragma unroll
    for (int f = 0; f < 16; f++) sacc[f] = f32x4{0.f, 0.f, 0.f, 0.f};
#pragma unroll
    for (int f = 0; f < 16; f++) if (f < nf) {
#pragma unroll
      for (int dc = 0; dc < 2; dc++) {
        short8 kf = *(const short8*)&k_sm[(f * 16 + fr) * KPAD + dc * 32 + fc];
        sacc[f] = __builtin_amdgcn_mfma_f32_16x16x32_bf16(aq[dc], kf, sacc[f], 0, 0, 0);
      }
    }
    float mr[4] = {-3e38f, -3e38f, -3e38f, -3e38f};
#pragma unroll
    for (int f = 0; f < 16; f++) if (f < nf) {
#pragma unroll
      for (int r = 0; r < 4; r++) {
        float sv = sacc[f][r] * 0.125f;
        if (f * 16 + fr > qr0 + rq + r) sv = -3e38f;
        sacc[f][r] = sv;
        mr[r] = fmaxf(mr[r], sv);
      }
    }
#pragma unroll
    for (int msk = 1; msk < 16; msk <<= 1) {
#pragma unroll
      for (int r = 0; r < 4; r++) mr[r] = fmaxf(mr[r], __shfl_xor(mr[r], msk));
    }
    float ls[4] = {0.f, 0.f, 0.f, 0.f};
#pragma unroll
    for (int f = 0; f < 16; f++) if (f < nf) {
#pragma unroll
      for (int r = 0; r < 4; r++) {
        float p = __expf(sacc[f][r] - mr[r]);
        sacc[f][r] = p;
        ls[r] += p;
      }
    }
#pragma unroll
    for (int msk = 1; msk < 16; msk <<= 1) {
#pragma unroll
      for (int r = 0; r < 4; r++) ls[r] += __shfl_xor(ls[r], msk);
    }
#pragma unroll
    for (int f = 0; f < 16; f++) if (f < nf) {
#pragma unroll
      for (int r = 0; r < 4; r++)
        pw[(rq + r) * PPAD + f * 16 + fr] = f2bf(sacc[f][r]);
    }
    if (nf & 1) {
#pragma unroll
      for (int r = 0; r < 4; r++) pw[(rq + r) * PPAD + nf * 16 + fr] = 0;
    }
    f32x4 oc[4];
#pragma unroll
    for (int n = 0; n < 4; n++) oc[n] = f32x4{0.f, 0.f, 0.f, 0.f};
    const int kcs = (nf + 1) >> 1;
#pragma unroll
    for (int kc = 0; kc < 8; ++kc) if (kc < kcs) {
      short8 pa = *(const short8*)&pw[fr * PPAD + kc * 32 + fc];
#pragma unroll
      for (int n = 0; n < 4; n++) {
        short8 vf = *(const short8*)&vt_sm[(n * 16 + fr) * VPAD + kc * 32 + fc];
        oc[n] = __builtin_amdgcn_mfma_f32_16x16x32_bf16(pa, vf, oc[n], 0, 0, 0);
      }
    }
    float inv[4];
#pragma unroll
    for (int r = 0; r < 4; r++) inv[r] = 1.f / ls[r];
#pragma unroll
    for (int n = 0; n < 4; n++) {
#pragma unroll
      for (int r = 0; r < 4; r++)
        ob[obase + (size_t)(qr0 + rq + r) * 384 + n * 16 + fr] = f2bf(oc[n][r] * inv[r]);
    }
  }
}

// ---------------- orchestration ---------------------------------------------
extern "C" void kernel_launch(void* const* d_in, const int* in_sizes, int n_in,
                              void* d_out, int out_size, void* d_ws, size_t ws_size,
                              hipStream_t stream) {
  const float* x   = (const float*)d_in[0];
  const float* Wq  = (const float*)d_in[1];
  const float* Wk  = (const float*)d_in[2];
  const float* Wv  = (const float*)d_in[3];
  const float* Wo  = (const float*)d_in[4];
  const float* bo  = (const float*)d_in[5];
  const float* W1  = (const float*)d_in[6];
  const float* b1  = (const float*)d_in[7];
  const float* W2  = (const float*)d_in[8];
  const float* b2  = (const float*)d_in[9];
  const float* g1  = (const float*)d_in[10];
  const float* be1 = (const float*)d_in[11];
  const float* g2  = (const float*)d_in[12];
  const float* be2 = (const float*)d_in[13];
  float* out = (float*)d_out;
  char* ws = (char*)d_ws;

  bfu* wqkvT = (bfu*)(ws + 0);          // 1152x384 bf16
  bfu* woT   = (bfu*)(ws + 884736);
  bfu* w1T   = (bfu*)(ws + 1179648);    // 1536x384
  bfu* w2T   = (bfu*)(ws + 2359296);    // 384x1536
  char* H    = ws + 3538944;            // 50.3 MB: h2
  char* BIG  = H + 50331648;            // 201.3 MB
  bfu* hb    = (bfu*)BIG;
  bfu* qkvb  = (bfu*)(BIG + 50331648);
  bfu* attnb = (bfu*)BIG;
  bfu* h2b   = (bfu*)H;
  bfu* ab    = (bfu*)BIG;

  // 1) all weight transposes (one launch)
  transpose_all<<<6912, 256, 0, stream>>>(Wq, Wk, Wv, Wo, W1, W2, wqkvT, woT, w1T, w2T);

  // 2) LN1
  ln_kernel<<<16384, 256, 0, stream>>>(x, g1, be1, hb);

  // 3) fused QKV GEMM (N=1152): 256 m-tiles x 6 n-tiles of 256x192
  gemm_ph<8, 3, 0, 0, 0, 1><<<1536, 512, 0, stream>>>(hb, wqkvT, nullptr, nullptr, qkvb, 1152, 384, 6);

  // 4) fused causal attention
  attn_kernel<<<1536, 512, 0, stream>>>(qkvb, attnb);

  // 5) proj + bias + residual(x) + LN2 fused -> h2 (bf16)
  row_gemm<<<512, 512, 0, stream>>>(attnb, woT, bo, x, g2, be2, h2b, 384);

  // 6) FFN1 (+bias+ReLU): 256 m-tiles x 6 n-tiles of 256x256
  gemm_ph<8, 4, 1, 1, 0, 1><<<1536, 512, 0, stream>>>(h2b, w1T, b1, nullptr, ab, 1536, 384, 6);

  // 7) FFN2 + bias + residual(x) -> out (fp32): 512 m-tiles x 1 n-tile of 128x384
  gemm_ph<4, 6, 1, 0, 1, 0><<<512, 512, 0, stream>>>(ab, w2T, b2, x, out, 384, 1536, 1);
}

// Round 14
// 465.417 us; speedup vs baseline: 1.5052x; 1.0268x over previous
//
#include <hip/hip_runtime.h>
#include <hip/hip_bf16.h>

typedef unsigned short bfu;
typedef __attribute__((ext_vector_type(8))) short short8;
typedef __attribute__((ext_vector_type(4))) float f32x4;

__device__ __forceinline__ bfu f2bf(float f) {
  return __builtin_bit_cast(bfu, __float2bfloat16(f));
}

__device__ __forceinline__ void gld16(const void* g, void* l) {
  __builtin_amdgcn_global_load_lds(
      (const __attribute__((address_space(1))) void*)g,
      (__attribute__((address_space(3))) void*)l, 16, 0, 0);
}

// ---- swizzle for [rows][64]-bf16 tiles (128B rows, 8 x 16B slots per row)
__device__ __forceinline__ int swz8(int row, int sl) {
  return (row << 7) + (((sl ^ (row & 7)) & 7) << 4);
}

// ---- swizzle for [rows][32]-bf16 tiles (64B rows) used by row_gemm --------
__device__ __forceinline__ int swz(int row, int slot) {
  const int unit = row >> 1;
  const int s8 = ((row & 1) << 2) | slot;
  return (unit << 7) + (((s8 ^ unit) & 7) << 4) + ((s8 >> 3) << 7);
}
__device__ __forceinline__ void unswz(int p, int& row, int& colel) {
  const int unit = p >> 7;
  const int s8 = ((p >> 4) & 7) ^ (unit & 7);
  row = (unit << 1) | (s8 >> 2);
  colel = (s8 & 3) << 3;
}

// ---------------- all weight transposes in ONE launch -----------------------
__global__ void transpose_all(const float* __restrict__ Wq, const float* __restrict__ Wk,
                              const float* __restrict__ Wv, const float* __restrict__ Wo,
                              const float* __restrict__ W1, const float* __restrict__ W2,
                              bfu* __restrict__ wqkvT, bfu* __restrict__ woT,
                              bfu* __restrict__ w1T, bfu* __restrict__ w2T) {
  int idx = blockIdx.x * 256 + threadIdx.x;
  if (idx < 4 * 147456) {
    int r = idx / 147456, i = idx - r * 147456;
    int k = i / 384, n = i - k * 384;
    const float* W = r == 0 ? Wq : r == 1 ? Wk : r == 2 ? Wv : Wo;
    bfu* dst = r < 3 ? wqkvT + r * 147456 : woT;
    dst[n * 384 + k] = f2bf(W[i]);
  } else if (idx < 4 * 147456 + 589824) {
    int i = idx - 4 * 147456;                    // W1: [384][1536]
    int k = i / 1536, n = i - k * 1536;
    w1T[n * 384 + k] = f2bf(W1[i]);
  } else if (idx < 4 * 147456 + 2 * 589824) {
    int i = idx - 4 * 147456 - 589824;           // W2: [1536][384]
    int k = i / 384, n = i - k * 384;
    w2T[(size_t)n * 1536 + k] = f2bf(W2[i]);
  }
}

// ---------------- LayerNorm: one wave per row of 384 ------------------------
__launch_bounds__(256)
__global__ void ln_kernel(const float* __restrict__ in, const float* __restrict__ g,
                          const float* __restrict__ be, bfu* __restrict__ out) {
  const int wv = threadIdx.x >> 6, ln = threadIdx.x & 63;
  const size_t row = (size_t)blockIdx.x * 4 + wv;
  const float* p = in + row * 384;
  float v[6], s = 0.f, ss = 0.f;
#pragma unroll
  for (int i = 0; i < 6; i++) { v[i] = p[i * 64 + ln]; s += v[i]; ss += v[i] * v[i]; }
#pragma unroll
  for (int m = 1; m < 64; m <<= 1) { s += __shfl_xor(s, m); ss += __shfl_xor(ss, m); }
  const float mean = s * (1.f / 384.f);
  const float rs = rsqrtf(ss * (1.f / 384.f) - mean * mean + 1e-5f);
  bfu* q = out + row * 384;
#pragma unroll
  for (int i = 0; i < 6; i++) {
    const int c = i * 64 + ln;
    q[c] = f2bf((v[i] - mean) * rs * g[c] + be[c]);
  }
}

// ---------------- fat-tile 4-phase GEMM: C[M,N] = A[M,K] @ Bt[N,K]^T --------
// R7 K-loop (verified) + R13 coalesced epilogue. This round: 128x192 tiles
// (WM=4, WN=3) -> 80KB LDS -> 2 blocks/CU, so barrier/drain gaps of one
// block are absorbed by the other (m114 wave-overlap mechanism).
template <int WM, int WN, int BIAS, int RELU, int RES, int OUTBF>
__launch_bounds__(512)
__global__ void gemm_ph(const bfu* __restrict__ A, const bfu* __restrict__ Bt,
                        const float* __restrict__ bias, const float* __restrict__ res,
                        void* __restrict__ Cout, int N, int K, int ntn) {
  constexpr int BM = WM * 32;
  constexpr int BN = WN * 64;
  constexpr int ACH = BM / 64;     // A 1KB-chunks per wave
  constexpr int BCH = BN / 64;     // B 1KB-chunks per wave
  __shared__ bfu sm[2][(BM + BN) * 64];
  const int tid = threadIdx.x;
  const int wv = tid >> 6, ln = tid & 63;
  const int cpx = gridDim.x >> 3;            // grid % 8 == 0 at all call sites
  const int wg = (blockIdx.x & 7) * cpx + (blockIdx.x >> 3);
  const int bm = wg / ntn, bn = wg - bm * ntn;
  const int m0 = bm * BM, n0 = bn * BN;
  const int wr = wv >> 2, wc = wv & 3;       // 2m x 4n wave grid
  const int fr = ln & 15, fslot = ln >> 4;
  const int lr = ln >> 3, lsl = (ln & 7) ^ lr;   // staging row / logical slot

  f32x4 acc[WM][WN];
#pragma unroll
  for (int i = 0; i < WM; i++)
#pragma unroll
    for (int j = 0; j < WN; j++) acc[i][j] = f32x4{0.f, 0.f, 0.f, 0.f};

  auto stageA = [&](int s, int kt) {
    char* smA = (char*)sm[s];
    const int col = (kt << 6) + (lsl << 3);
#pragma unroll
    for (int i = 0; i < ACH; ++i) {
      const int c = wv * ACH + i;
      gld16(A + (size_t)(m0 + (c << 3) + lr) * K + col, smA + (c << 10));
    }
  };
  auto stageB = [&](int s, int kt) {
    char* smB = (char*)sm[s] + BM * 128;
    const int col = (kt << 6) + (lsl << 3);
#pragma unroll
    for (int i = 0; i < BCH; ++i) {
      const int c = wv * BCH + i;
      gld16(Bt + (size_t)(n0 + (c << 3) + lr) * K + col, smB + (c << 10));
    }
  };

  const int nk = K >> 6;
  stageA(0, 0);
  stageB(0, 0);
  asm volatile("s_waitcnt vmcnt(0)" ::: "memory");
  __builtin_amdgcn_s_barrier();

  for (int kt = 0; kt < nk; ++kt) {
    const int cur = kt & 1;
    const char* smA = (const char*)sm[cur];
    const char* smB = smA + BM * 128;
    short8 bf[2][WN];
#pragma unroll
    for (int ph = 0; ph < 4; ++ph) {
      const int mh = ph >> 1, ks = ph & 1;
      short8 af[WM / 2];
#pragma unroll
      for (int i = 0; i < WM / 2; ++i)
        af[i] = *(const short8*)(smA +
            swz8(wr * (WM * 16) + (mh * (WM / 2) + i) * 16 + fr, ks * 4 + fslot));
      if (mh == 0) {
#pragma unroll
        for (int ni = 0; ni < WN; ++ni)
          bf[ks][ni] = *(const short8*)(smB +
              swz8(wc * (WN * 16) + ni * 16 + fr, ks * 4 + fslot));
      }
      if (kt + 1 < nk) {
        if (ph == 0) stageA(cur ^ 1, kt + 1);
        if (ph == 1) stageB(cur ^ 1, kt + 1);
      }
      __builtin_amdgcn_s_barrier();
      asm volatile("s_waitcnt lgkmcnt(0)" ::: "memory");
      __builtin_amdgcn_sched_barrier(0);
      __builtin_amdgcn_s_setprio(1);
#pragma unroll
      for (int i = 0; i < WM / 2; ++i)
#pragma unroll
        for (int ni = 0; ni < WN; ++ni)
          acc[mh * (WM / 2) + i][ni] = __builtin_amdgcn_mfma_f32_16x16x32_bf16(
              af[i], bf[ks][ni], acc[mh * (WM / 2) + i][ni], 0, 0, 0);
      __builtin_amdgcn_s_setprio(0);
      __builtin_amdgcn_s_barrier();
    }
    if (kt + 1 < nk) {
      asm volatile("s_waitcnt vmcnt(0)" ::: "memory");
      __builtin_amdgcn_s_barrier();
    }
  }

  // ---- coalesced epilogue (LDS bufs dead; per-wave private scratch) --------
  const int rq = fslot << 2;
  if (OUTBF) {
    constexpr int SSTR = WN * 16 + 8;                    // shorts per scratch row
    bfu* scr = (bfu*)((char*)sm + wv * (SSTR * 16 * 2));
#pragma unroll
    for (int mi = 0; mi < WM; mi++) {
#pragma unroll
      for (int ni = 0; ni < WN; ni++) {
        const int col = n0 + wc * (WN * 16) + ni * 16 + fr;
        float bv = 0.f;
        if (BIAS) bv = bias[col];
#pragma unroll
        for (int r = 0; r < 4; r++) {
          float v = acc[mi][ni][r] + bv;
          if (RELU) v = fmaxf(v, 0.f);
          scr[(rq + r) * SSTR + ni * 16 + fr] = f2bf(v);
        }
      }
      constexpr int NCH = WN * 2 * 16;                   // 16B chunks (16 rows x WN*2)
#pragma unroll
      for (int f0 = 0; f0 < NCH; f0 += 64) {
        const int f = f0 + ln;
        if (f < NCH) {
          const int row = f / (WN * 2), c16 = f - row * (WN * 2);
          short8 v = *(const short8*)((const char*)scr + row * SSTR * 2 + c16 * 16);
          const int grow = m0 + wr * (WM * 16) + mi * 16 + row;
          const int gcol = n0 + wc * (WN * 16) + c16 * 8;
          *(short8*)((bfu*)Cout + (size_t)grow * N + gcol) = v;
        }
      }
    }
  } else {
    constexpr int SSTR = WN * 16 + 4;                    // floats per scratch row
    float* scr = (float*)((char*)sm + wv * (SSTR * 16 * 4));
#pragma unroll
    for (int mi = 0; mi < WM; mi++) {
#pragma unroll
      for (int ni = 0; ni < WN; ni++) {
#pragma unroll
        for (int r = 0; r < 4; r++)
          scr[(rq + r) * SSTR + ni * 16 + fr] = acc[mi][ni][r];
      }
      constexpr int NCH = WN * 4 * 16;                   // 4-float chunks (16 rows x WN*4)
#pragma unroll
      for (int f0 = 0; f0 < NCH; f0 += 64) {
        const int f = f0 + ln;
        if (f < NCH) {
          const int row = f / (WN * 4), cf = (f - row * (WN * 4)) * 4;
          f32x4 v = *(const f32x4*)(scr + row * SSTR + cf);
          const int grow = m0 + wr * (WM * 16) + mi * 16 + row;
          const int gcol = n0 + wc * (WN * 16) + cf;
          const size_t idx = (size_t)grow * N + gcol;
          if (BIAS) v += *(const f32x4*)(bias + gcol);
          if (RELU) {
#pragma unroll
            for (int e = 0; e < 4; e++) v[e] = fmaxf(v[e], 0.f);
          }
          if (RES) v += *(const f32x4*)(res + idx);
          *(f32x4*)((float*)Cout + idx) = v;
        }
      }
    }
  }
}

// ---------------- full-row GEMM (proj + LN2 fusion): C[M,384] ---------------
// NEW: LN output staged into dead b_sm, then coalesced linear copy-out.
__launch_bounds__(512)
__global__ void row_gemm(const bfu* __restrict__ A, const bfu* __restrict__ Bt,
                         const float* __restrict__ bias, const float* __restrict__ res,
                         const float* __restrict__ g, const float* __restrict__ be,
                         void* __restrict__ Cout, int K) {
  __shared__ bfu a_sm[4][128 * 32];
  __shared__ bfu b_sm[4][384 * 32];        // reused as [128][384] bf16 scratch
  __shared__ float lnp[4][128][2];
  const int tid = threadIdx.x;
  const int wv = tid >> 6, ln = tid & 63;
  const int wr = wv >> 2, wc = wv & 3;
  const int fr = ln & 15, fslot = ln >> 4;
  const int m0 = blockIdx.x << 7;

  f32x4 acc[4][6];
#pragma unroll
  for (int i = 0; i < 4; i++)
#pragma unroll
    for (int j = 0; j < 6; j++) acc[i][j] = f32x4{0.f, 0.f, 0.f, 0.f};

  auto stage = [&](int buf, int kt) {
#pragma unroll
    for (int i = 0; i < 4; ++i) {
      const int c = wv * 4 + i;
      const int cc = (c < 8) ? c : (c - 8);
      const int p = cc * 1024 + (ln << 4);
      int r, colel;
      unswz(p, r, colel);
      const int col = kt * 32 + colel;
      if (c < 8)
        gld16(A + (size_t)(m0 + r) * K + col, (char*)a_sm[buf] + cc * 1024);
      else
        gld16(Bt + (size_t)r * K + col, (char*)b_sm[buf] + cc * 1024);
    }
  };

  const int nk = K >> 5;
#pragma unroll
  for (int i = 0; i < 3; ++i)
    if (i < nk) stage(i, i);

  for (int kt = 0; kt < nk; ++kt) {
    const int rem = nk - 1 - kt;
    if (rem >= 2)      asm volatile("s_waitcnt vmcnt(8)" ::: "memory");
    else if (rem == 1) asm volatile("s_waitcnt vmcnt(4)" ::: "memory");
    else               asm volatile("s_waitcnt vmcnt(0)" ::: "memory");
    __builtin_amdgcn_s_barrier();
    __builtin_amdgcn_sched_barrier(0);
    if (kt + 3 < nk) stage((kt + 3) & 3, kt + 3);
    const int cb = kt & 3;
    short8 af[4], bfr[6];
#pragma unroll
    for (int mi = 0; mi < 4; mi++)
      af[mi] = *(const short8*)((const char*)a_sm[cb] + swz(wr * 64 + mi * 16 + fr, fslot));
#pragma unroll
    for (int ni = 0; ni < 6; ni++)
      bfr[ni] = *(const short8*)((const char*)b_sm[cb] + swz(wc * 96 + ni * 16 + fr, fslot));
    __builtin_amdgcn_s_setprio(1);
#pragma unroll
    for (int mi = 0; mi < 4; mi++)
#pragma unroll
      for (int ni = 0; ni < 6; ni++)
        acc[mi][ni] = __builtin_amdgcn_mfma_f32_16x16x32_bf16(af[mi], bfr[ni], acc[mi][ni], 0, 0, 0);
    __builtin_amdgcn_s_setprio(0);
  }

  const int rq = (ln >> 4) << 2;
#pragma unroll
  for (int mi = 0; mi < 4; mi++) {
    const int row = wr * 64 + mi * 16 + rq;
#pragma unroll
    for (int ni = 0; ni < 6; ni++) {
      const int col = wc * 96 + ni * 16 + fr;
      const float bv = bias[col];
#pragma unroll
      for (int r = 0; r < 4; r++)
        acc[mi][ni][r] += bv + res[(size_t)(m0 + row + r) * 384 + col];
    }
  }

#pragma unroll
  for (int mi = 0; mi < 4; mi++) {
    float s[4] = {0.f, 0.f, 0.f, 0.f}, ss[4] = {0.f, 0.f, 0.f, 0.f};
#pragma unroll
    for (int ni = 0; ni < 6; ni++)
#pragma unroll
      for (int r = 0; r < 4; r++) {
        const float v = acc[mi][ni][r];
        s[r] += v; ss[r] += v * v;
      }
#pragma unroll
    for (int m = 1; m < 16; m <<= 1)
#pragma unroll
      for (int r = 0; r < 4; r++) {
        s[r] += __shfl_xor(s[r], m);
        ss[r] += __shfl_xor(ss[r], m);
      }
    if (fr == 0) {
#pragma unroll
      for (int r = 0; r < 4; r++) {
        lnp[wc][wr * 64 + mi * 16 + rq + r][0] = s[r];
        lnp[wc][wr * 64 + mi * 16 + rq + r][1] = ss[r];
      }
    }
  }
  __syncthreads();                      // lnp ready; K-loop LDS reads done
  bfu* scr = &b_sm[0][0];               // [128][384] bf16 scratch (b_sm dead)
#pragma unroll
  for (int mi = 0; mi < 4; mi++) {
#pragma unroll
    for (int r = 0; r < 4; r++) {
      const int row = wr * 64 + mi * 16 + rq + r;
      const float sm = lnp[0][row][0] + lnp[1][row][0] + lnp[2][row][0] + lnp[3][row][0];
      const float sq = lnp[0][row][1] + lnp[1][row][1] + lnp[2][row][1] + lnp[3][row][1];
      const float mean = sm * (1.f / 384.f);
      const float rs = rsqrtf(sq * (1.f / 384.f) - mean * mean + 1e-5f);
#pragma unroll
      for (int ni = 0; ni < 6; ni++) {
        const int col = wc * 96 + ni * 16 + fr;
        scr[row * 384 + col] = f2bf((acc[mi][ni][r] - mean) * rs * g[col] + be[col]);
      }
    }
  }
  __syncthreads();
  // coalesced copy-out: 128 rows x 384 bf16 = 6144 short8 chunks, 12/thread
#pragma unroll
  for (int i = 0; i < 12; ++i) {
    const int c = i * 512 + tid;
    const int row = c / 48, off = (c - row * 48) * 8;
    *(short8*)((bfu*)Cout + (size_t)(m0 + row) * 384 + off) =
        *(const short8*)(scr + row * 384 + off);
  }
}

// ---------------- fused causal attention: 1 block per (b,h), 8 waves --------
#define KPAD 72
#define VPAD 264
#define PPAD 264

__launch_bounds__(512)
__global__ void attn_kernel(const bfu* __restrict__ qkv, bfu* __restrict__ ob) {
  __shared__ bfu k_sm[256 * KPAD];
  __shared__ bfu vt_sm[64 * VPAD];
  __shared__ bfu p_sm[8 * 16 * PPAD];
  const int b = blockIdx.x / 6, h = blockIdx.x - b * 6;
  const int tid = threadIdx.x;
  const int wv = tid >> 6, ln = tid & 63;
  const int fr = ln & 15, fc = (ln >> 4) << 3;
  const size_t inbase = (size_t)b * 256 * 1152 + h * 64;
  const bfu* qb = qkv + inbase;
  const bfu* kb = qkv + inbase + 384;
  const bfu* vb = qkv + inbase + 768;
  const size_t obase = (size_t)b * 256 * 384 + h * 64;

  {
    const int row = tid >> 1;
    const int dh = (tid & 1) << 5;
    const bfu* kg = kb + (size_t)row * 1152 + dh;
    const bfu* vg = vb + (size_t)row * 1152 + dh;
#pragma unroll
    for (int i = 0; i < 4; i++) {
      short8 t8 = *(const short8*)(kg + i * 8);
      *(short8*)&k_sm[row * KPAD + dh + i * 8] = t8;
      short8 v8 = *(const short8*)(vg + i * 8);
#pragma unroll
      for (int j = 0; j < 8; j++)
        vt_sm[(dh + i * 8 + j) * VPAD + row] = (bfu)v8[j];
    }
  }
  __syncthreads();

  bfu* pw = &p_sm[wv * 16 * PPAD];
  const int rq = (ln >> 4) << 2;

#pragma unroll
  for (int si = 0; si < 2; ++si) {
    const int s = si ? (15 - wv) : wv;
    const int qr0 = s << 4;
    const int nf = s + 1;
    short8 aq[2];
#pragma unroll
    for (int dc = 0; dc < 2; dc++)
      aq[dc] = *(const short8*)(qb + (size_t)(qr0 + fr) * 1152 + dc * 32 + fc);

    f32x4 sacc[16];
#pragma unroll
    for (int f = 0; f < 16; f++) sacc[f] = f32x4{0.f, 0.f, 0.f, 0.f};
#pragma unroll
    for (int f = 0; f < 16; f++) if (f < nf) {
#pragma unroll
      for (int dc = 0; dc < 2; dc++) {
        short8 kf = *(const short8*)&k_sm[(f * 16 + fr) * KPAD + dc * 32 + fc];
        sacc[f] = __builtin_amdgcn_mfma_f32_16x16x32_bf16(aq[dc], kf, sacc[f], 0, 0, 0);
      }
    }
    float mr[4] = {-3e38f, -3e38f, -3e38f, -3e38f};
#pragma unroll
    for (int f = 0; f < 16; f++) if (f < nf) {
#pragma unroll
      for (int r = 0; r < 4; r++) {
        float sv = sacc[f][r] * 0.125f;
        if (f * 16 + fr > qr0 + rq + r) sv = -3e38f;
        sacc[f][r] = sv;
        mr[r] = fmaxf(mr[r], sv);
      }
    }
#pragma unroll
    for (int msk = 1; msk < 16; msk <<= 1) {
#pragma unroll
      for (int r = 0; r < 4; r++) mr[r] = fmaxf(mr[r], __shfl_xor(mr[r], msk));
    }
    float ls[4] = {0.f, 0.f, 0.f, 0.f};
#pragma unroll
    for (int f = 0; f < 16; f++) if (f < nf) {
#pragma unroll
      for (int r = 0; r < 4; r++) {
        float p = __expf(sacc[f][r] - mr[r]);
        sacc[f][r] = p;
        ls[r] += p;
      }
    }
#pragma unroll
    for (int msk = 1; msk < 16; msk <<= 1) {
#pragma unroll
      for (int r = 0; r < 4; r++) ls[r] += __shfl_xor(ls[r], msk);
    }
#pragma unroll
    for (int f = 0; f < 16; f++) if (f < nf) {
#pragma unroll
      for (int r = 0; r < 4; r++)
        pw[(rq + r) * PPAD + f * 16 + fr] = f2bf(sacc[f][r]);
    }
    if (nf & 1) {
#pragma unroll
      for (int r = 0; r < 4; r++) pw[(rq + r) * PPAD + nf * 16 + fr] = 0;
    }
    f32x4 oc[4];
#pragma unroll
    for (int n = 0; n < 4; n++) oc[n] = f32x4{0.f, 0.f, 0.f, 0.f};
    const int kcs = (nf + 1) >> 1;
#pragma unroll
    for (int kc = 0; kc < 8; ++kc) if (kc < kcs) {
      short8 pa = *(const short8*)&pw[fr * PPAD + kc * 32 + fc];
#pragma unroll
      for (int n = 0; n < 4; n++) {
        short8 vf = *(const short8*)&vt_sm[(n * 16 + fr) * VPAD + kc * 32 + fc];
        oc[n] = __builtin_amdgcn_mfma_f32_16x16x32_bf16(pa, vf, oc[n], 0, 0, 0);
      }
    }
    float inv[4];
#pragma unroll
    for (int r = 0; r < 4; r++) inv[r] = 1.f / ls[r];
#pragma unroll
    for (int n = 0; n < 4; n++) {
#pragma unroll
      for (int r = 0; r < 4; r++)
        ob[obase + (size_t)(qr0 + rq + r) * 384 + n * 16 + fr] = f2bf(oc[n][r] * inv[r]);
    }
  }
}

// ---------------- orchestration ---------------------------------------------
extern "C" void kernel_launch(void* const* d_in, const int* in_sizes, int n_in,
                              void* d_out, int out_size, void* d_ws, size_t ws_size,
                              hipStream_t stream) {
  const float* x   = (const float*)d_in[0];
  const float* Wq  = (const float*)d_in[1];
  const float* Wk  = (const float*)d_in[2];
  const float* Wv  = (const float*)d_in[3];
  const float* Wo  = (const float*)d_in[4];
  const float* bo  = (const float*)d_in[5];
  const float* W1  = (const float*)d_in[6];
  const float* b1  = (const float*)d_in[7];
  const float* W2  = (const float*)d_in[8];
  const float* b2  = (const float*)d_in[9];
  const float* g1  = (const float*)d_in[10];
  const float* be1 = (const float*)d_in[11];
  const float* g2  = (const float*)d_in[12];
  const float* be2 = (const float*)d_in[13];
  float* out = (float*)d_out;
  char* ws = (char*)d_ws;

  bfu* wqkvT = (bfu*)(ws + 0);          // 1152x384 bf16
  bfu* woT   = (bfu*)(ws + 884736);
  bfu* w1T   = (bfu*)(ws + 1179648);    // 1536x384
  bfu* w2T   = (bfu*)(ws + 2359296);    // 384x1536
  char* H    = ws + 3538944;            // 50.3 MB: h2
  char* BIG  = H + 50331648;            // 201.3 MB
  bfu* hb    = (bfu*)BIG;
  bfu* qkvb  = (bfu*)(BIG + 50331648);
  bfu* attnb = (bfu*)BIG;
  bfu* h2b   = (bfu*)H;
  bfu* ab    = (bfu*)BIG;

  // 1) all weight transposes (one launch)
  transpose_all<<<6912, 256, 0, stream>>>(Wq, Wk, Wv, Wo, W1, W2, wqkvT, woT, w1T, w2T);

  // 2) LN1
  ln_kernel<<<16384, 256, 0, stream>>>(x, g1, be1, hb);

  // 3) fused QKV GEMM (N=1152): 512 m-tiles x 6 n-tiles of 128x192
  gemm_ph<4, 3, 0, 0, 0, 1><<<3072, 512, 0, stream>>>(hb, wqkvT, nullptr, nullptr, qkvb, 1152, 384, 6);

  // 4) fused causal attention
  attn_kernel<<<1536, 512, 0, stream>>>(qkvb, attnb);

  // 5) proj + bias + residual(x) + LN2 fused -> h2 (bf16)
  row_gemm<<<512, 512, 0, stream>>>(attnb, woT, bo, x, g2, be2, h2b, 384);

  // 6) FFN1 (+bias+ReLU): 512 m-tiles x 8 n-tiles of 128x192
  gemm_ph<4, 3, 1, 1, 0, 1><<<4096, 512, 0, stream>>>(h2b, w1T, b1, nullptr, ab, 1536, 384, 8);

  // 7) FFN2 + bias + residual(x) -> out (fp32): 512 m-tiles x 2 n-tiles of 128x192
  gemm_ph<4, 3, 1, 0, 1, 0><<<1024, 512, 0, stream>>>(ab, w2T, b2, x, out, 384, 1536, 2);
}